// Round 2
// baseline (1141.503 us; speedup 1.0000x reference)
//
#include <hip/hip_runtime.h>
#include <cstdio>
#include <cstdint>

// Problem constants
#define BATCH 8
#define CH    512
#define OC3   1536      // 3*CH
#define NPIX  4096      // 64*64
#define HEADS 8
#define HDIM  64
#define KDEPTH 512      // GEMM K
#define SCALE 0.125f    // 64^-0.5

// ---------------------------------------------------------------------------
// GEMM: C[b][m][n] = sum_k A[m][k] * Bmat[b*b_stride + k][n] + bias[m]
// A: [M][512] row-major (weights). b_stride/c_stride are row counts per batch.
// Tile: BM=64 BN=64 BK=16, 256 threads, 4x4 per thread.
// ---------------------------------------------------------------------------
__global__ __launch_bounds__(256) void sgemm_bias_kernel(
    const float* __restrict__ A, const float* __restrict__ Bmat,
    const float* __restrict__ bias, float* __restrict__ Cm,
    int M, int b_stride, int c_stride)
{
    const int b  = blockIdx.z;
    const int m0 = blockIdx.y * 64;
    const int n0 = blockIdx.x * 64;
    const float* Bp = Bmat + (size_t)b * b_stride * NPIX;
    float* Cp       = Cm   + (size_t)b * c_stride * NPIX;

    __shared__ float As[16][68];   // As[k][m] (transposed)
    __shared__ float Bs[16][68];   // Bs[k][n]

    const int t  = threadIdx.x;
    const int tx = t & 15, ty = t >> 4;
    const int tm = ty * 4, tn = tx * 4;

    float acc[4][4] = {};

    for (int k0 = 0; k0 < KDEPTH; k0 += 16) {
        {
            const int i  = t >> 2;          // row (m) 0..63
            const int j4 = (t & 3) * 4;     // k offset
            const float4 av = *(const float4*)(A + (size_t)(m0 + i) * KDEPTH + k0 + j4);
            As[j4 + 0][i] = av.x; As[j4 + 1][i] = av.y;
            As[j4 + 2][i] = av.z; As[j4 + 3][i] = av.w;
        }
        {
            const int j  = t >> 4;          // k 0..15
            const int n4 = (t & 15) * 4;
            *(float4*)(&Bs[j][n4]) = *(const float4*)(Bp + (size_t)(k0 + j) * NPIX + n0 + n4);
        }
        __syncthreads();
        #pragma unroll
        for (int kk = 0; kk < 16; ++kk) {
            const float4 a4 = *(const float4*)&As[kk][tm];
            const float4 b4 = *(const float4*)&Bs[kk][tn];
            const float a[4]  = {a4.x, a4.y, a4.z, a4.w};
            const float bb[4] = {b4.x, b4.y, b4.z, b4.w};
            #pragma unroll
            for (int i = 0; i < 4; ++i)
                #pragma unroll
                for (int j = 0; j < 4; ++j)
                    acc[i][j] = fmaf(a[i], bb[j], acc[i][j]);
        }
        __syncthreads();
    }

    #pragma unroll
    for (int i = 0; i < 4; ++i) {
        const float bv = bias[m0 + tm + i];
        #pragma unroll
        for (int j = 0; j < 4; ++j)
            Cp[(size_t)(m0 + tm + i) * NPIX + n0 + tn + j] = acc[i][j] + bv;
    }
}

// ---------------------------------------------------------------------------
// Per (b,h): S[d][e] = SCALE * sum_n q[d,n]*k[e,n]; softmax rows -> attn
// ---------------------------------------------------------------------------
__global__ __launch_bounds__(256) void qk_softmax_kernel(
    const float* __restrict__ qkv, float* __restrict__ attn)
{
    const int bh = blockIdx.x;
    const int b = bh >> 3, h = bh & 7;
    const float* qbase = qkv + ((size_t)b * OC3 + h * HDIM) * NPIX;
    const float* kbase = qkv + ((size_t)b * OC3 + CH + h * HDIM) * NPIX;

    __shared__ float qs[64][68];   // qs[n_local][d]
    __shared__ float ks[64][68];   // ks[n_local][e]
    __shared__ float ss[64][68];   // scores [d][e]

    const int t  = threadIdx.x;
    const int tx = t & 15, ty = t >> 4;
    const int td = ty * 4, te = tx * 4;

    float acc[4][4] = {};

    for (int nc = 0; nc < 64; ++nc) {
        #pragma unroll
        for (int i = 0; i < 4; ++i) {
            const int lin = t + 256 * i;       // 0..1023
            const int row = lin >> 4;          // d or e: 0..63
            const int c4  = (lin & 15) * 4;    // n_local offset
            const float4 qv = *(const float4*)(qbase + (size_t)row * NPIX + nc * 64 + c4);
            qs[c4 + 0][row] = qv.x; qs[c4 + 1][row] = qv.y;
            qs[c4 + 2][row] = qv.z; qs[c4 + 3][row] = qv.w;
            const float4 kv = *(const float4*)(kbase + (size_t)row * NPIX + nc * 64 + c4);
            ks[c4 + 0][row] = kv.x; ks[c4 + 1][row] = kv.y;
            ks[c4 + 2][row] = kv.z; ks[c4 + 3][row] = kv.w;
        }
        __syncthreads();
        #pragma unroll
        for (int kk = 0; kk < 64; ++kk) {
            const float4 a4 = *(const float4*)&qs[kk][td];
            const float4 b4 = *(const float4*)&ks[kk][te];
            const float a[4]  = {a4.x, a4.y, a4.z, a4.w};
            const float bb[4] = {b4.x, b4.y, b4.z, b4.w};
            #pragma unroll
            for (int i = 0; i < 4; ++i)
                #pragma unroll
                for (int j = 0; j < 4; ++j)
                    acc[i][j] = fmaf(a[i], bb[j], acc[i][j]);
        }
        __syncthreads();
    }

    #pragma unroll
    for (int i = 0; i < 4; ++i)
        #pragma unroll
        for (int j = 0; j < 4; ++j)
            ss[td + i][te + j] = acc[i][j] * SCALE;
    __syncthreads();

    if (t < 64) {
        float m = -1e30f;
        for (int e = 0; e < 64; ++e) m = fmaxf(m, ss[t][e]);
        float s = 0.f;
        for (int e = 0; e < 64; ++e) { const float v = __expf(ss[t][e] - m); ss[t][e] = v; s += v; }
        const float inv = 1.f / s;
        float* arow = attn + ((size_t)bh * 64 + t) * 64;
        for (int e = 0; e < 64; ++e) arow[e] = ss[t][e] * inv;
    }
}

// ---------------------------------------------------------------------------
// attn_mean[b][d][e] = mean_h attn[b][h][d][e]
// ---------------------------------------------------------------------------
__global__ __launch_bounds__(256) void attn_mean_kernel(
    const float* __restrict__ attn, float* __restrict__ om)
{
    const int idx = blockIdx.x * 256 + threadIdx.x;   // 0..32767
    const int b = idx >> 12, de = idx & 4095;
    float s = 0.f;
    #pragma unroll
    for (int h = 0; h < 8; ++h)
        s += attn[(((size_t)b * 8 + h) << 12) + de];
    om[idx] = s * 0.125f;
}

// ---------------------------------------------------------------------------
// PV: outv[b*o_stride + h*64+d][n] = sum_e attn[b,h,d,e] * v[b][1024+h*64+e][n]
// outv aliases the (dead) Q region of qkv: channels 0..511, batch stride OC3.
// ---------------------------------------------------------------------------
__global__ __launch_bounds__(256) void pv_kernel(
    const float* __restrict__ attn, const float* __restrict__ qkv,
    float* __restrict__ outv, int o_stride)
{
    const int bh = blockIdx.y;
    const int b = bh >> 3, h = bh & 7;
    const int n = blockIdx.x * 256 + threadIdx.x;

    __shared__ float As[4096];   // attn[d][e] flat
    const float* ab = attn + (size_t)bh * 4096;
    #pragma unroll
    for (int i = 0; i < 4; ++i) {
        const int lin = threadIdx.x + 256 * i;   // 0..1023 float4s
        *(float4*)&As[lin * 4] = *(const float4*)(ab + lin * 4);
    }
    __syncthreads();

    const float* vbase = qkv + ((size_t)b * OC3 + 2 * CH + h * HDIM) * NPIX + n;
    float acc[64];
    #pragma unroll
    for (int d = 0; d < 64; ++d) acc[d] = 0.f;

    for (int e = 0; e < 64; ++e) {
        const float vv = vbase[(size_t)e * NPIX];
        #pragma unroll
        for (int d = 0; d < 64; ++d)
            acc[d] = fmaf(As[d * 64 + e], vv, acc[d]);
    }

    float* ob = outv + ((size_t)b * o_stride + h * HDIM) * NPIX + n;
    #pragma unroll
    for (int d = 0; d < 64; ++d) ob[(size_t)d * NPIX] = acc[d];
}

// ---------------------------------------------------------------------------
extern "C" void kernel_launch(void* const* d_in, const int* in_sizes, int n_in,
                              void* d_out, int out_size, void* d_ws, size_t ws_size,
                              hipStream_t stream)
{
    (void)in_sizes; (void)n_in; (void)out_size;
    const float* x      = (const float*)d_in[0];
    const float* qkv_w  = (const float*)d_in[1];
    const float* qkv_b  = (const float*)d_in[2];
    const float* proj_w = (const float*)d_in[3];
    const float* proj_b = (const float*)d_in[4];

    float* out       = (float*)d_out;                         // 8*512*4096
    float* attn_mean = out + (size_t)BATCH * CH * NPIX;       // 8*64*64

    const size_t qkv_bytes  = (size_t)BATCH * OC3 * NPIX * 4; // 192 MiB
    const size_t attn_bytes = (size_t)BATCH * HEADS * HDIM * HDIM * 4; // 1 MiB
    const size_t need = qkv_bytes + attn_bytes;               // 193 MiB
    if (ws_size < need) {
        fprintf(stderr, "[kernel_launch] ws_size=%zu < need=%zu — abort\n", ws_size, need);
        fflush(stderr);
        return;
    }

    float* qkv  = (float*)d_ws;
    float* attn = (float*)((char*)d_ws + qkv_bytes);
    float* outv = qkv;   // PV result goes into the dead Q region (batch stride OC3)

    // 1) QKV GEMM: [1536x512] x [b][512x4096] + bias
    sgemm_bias_kernel<<<dim3(NPIX / 64, OC3 / 64, BATCH), 256, 0, stream>>>(
        qkv_w, x, qkv_b, qkv, OC3, CH /*x batch stride*/, OC3);

    // 2) QK^T + softmax per (b,h)
    qk_softmax_kernel<<<dim3(BATCH * HEADS), 256, 0, stream>>>(qkv, attn);

    // 3) attn mean over heads (output 1)
    attn_mean_kernel<<<dim3(BATCH * HDIM * HDIM / 256), 256, 0, stream>>>(attn, attn_mean);

    // 4) PV -> Q region of qkv
    pv_kernel<<<dim3(NPIX / 256, BATCH * HEADS), 256, 0, stream>>>(attn, qkv, outv, OC3);

    // 5) proj GEMM: [512x512] x [b][512x4096] + bias -> output 0
    sgemm_bias_kernel<<<dim3(NPIX / 64, CH / 64, BATCH), 256, 0, stream>>>(
        proj_w, outv, proj_b, out, CH, OC3 /*outv batch stride*/, CH);
}

// Round 3
// 420.790 us; speedup vs baseline: 2.7128x; 2.7128x over previous
//
#include <hip/hip_runtime.h>
#include <cstdio>
#include <cstdint>

// Problem constants
#define BATCH 8
#define CH    512
#define OC3   1536      // 3*CH
#define NPIX  4096      // 64*64
#define HEADS 8
#define HDIM  64
#define KDEPTH 512      // GEMM K
#define SCALE 0.125f    // 64^-0.5

typedef __bf16 bf16;
typedef __bf16 bf16x8 __attribute__((ext_vector_type(8)));
typedef float  f32x4  __attribute__((ext_vector_type(4)));

// ---------------------------------------------------------------------------
// fp32 -> bf16 flat convert (weights)
// ---------------------------------------------------------------------------
__global__ __launch_bounds__(256) void convert_bf16_kernel(
    const float* __restrict__ in, bf16* __restrict__ out, int n)
{
    const int i = blockIdx.x * 256 + threadIdx.x;
    if (i < n) out[i] = (bf16)in[i];
}

// ---------------------------------------------------------------------------
// x [b][512][4096] fp32  ->  xt [b][4096][512] bf16 (transpose + convert)
// grid (4096/64, 512/64, 8), 256 threads, LDS float tile [64][65]
// ---------------------------------------------------------------------------
__global__ __launch_bounds__(256) void transpose_convert_kernel(
    const float* __restrict__ x, bf16* __restrict__ xt)
{
    const int b  = blockIdx.z;
    const int n0 = blockIdx.x * 64;
    const int c0 = blockIdx.y * 64;
    __shared__ float tile[64][65];
    const int t = threadIdx.x;
    const float* xp = x + (size_t)b * 512 * 4096;

    #pragma unroll
    for (int i = 0; i < 4; ++i) {
        const int lin = t + 256 * i;     // 0..1023 float4 chunks
        const int r   = lin >> 4;        // c-local 0..63
        const int c4  = (lin & 15) * 4;  // n-local
        const float4 v = *(const float4*)(xp + (size_t)(c0 + r) * 4096 + n0 + c4);
        tile[r][c4 + 0] = v.x; tile[r][c4 + 1] = v.y;
        tile[r][c4 + 2] = v.z; tile[r][c4 + 3] = v.w;
    }
    __syncthreads();

    bf16* op = xt + (size_t)b * 4096 * 512;
    #pragma unroll
    for (int i = 0; i < 2; ++i) {
        const int lin = t + 256 * i;     // 0..511 chunks of 8
        const int n   = lin >> 3;        // n-local 0..63
        const int c8  = (lin & 7) * 8;   // c-local
        bf16x8 v;
        #pragma unroll
        for (int jj = 0; jj < 8; ++jj) v[jj] = (bf16)tile[c8 + jj][n];
        *(bf16x8*)(op + (size_t)(n0 + n) * 512 + c0 + c8) = v;
    }
}

// ---------------------------------------------------------------------------
// MFMA GEMM: C[b][m][n] fp32 = sum_k A[m][k] * Bt[b][n][k] + bias[m]
// A: [M][512] bf16, Bt: [b][4096][512] bf16. 128x128 tile, BK=32,
// 256 thr = 4 waves (2x2), each wave 64x64 via 4x4 frags of 16x16x32.
// ---------------------------------------------------------------------------
__global__ __launch_bounds__(256) void mfma_gemm_kernel(
    const bf16* __restrict__ A, const bf16* __restrict__ Bt,
    const float* __restrict__ bias, float* __restrict__ C, int M)
{
    const int b  = blockIdx.z;
    const int m0 = blockIdx.y * 128;
    const int n0 = blockIdx.x * 128;
    const bf16* Bp = Bt + (size_t)b * NPIX * KDEPTH;
    float* Cp      = C  + (size_t)b * M * NPIX;

    __shared__ bf16 As[128 * 32];   // [row m][k] linear, 64B rows
    __shared__ bf16 Bs[128 * 32];   // [row n][k] linear

    const int t    = threadIdx.x;
    const int lane = t & 63;
    const int wave = t >> 6;
    const int wr   = wave >> 1, wc = wave & 1;

    f32x4 acc[4][4];
    const f32x4 zf = {0.f, 0.f, 0.f, 0.f};
    #pragma unroll
    for (int i = 0; i < 4; ++i)
        #pragma unroll
        for (int j = 0; j < 4; ++j) acc[i][j] = zf;

    for (int k0 = 0; k0 < KDEPTH; k0 += 32) {
        // stage 128x32 A and B tiles (reg-staged, int4 = 8 bf16)
        #pragma unroll
        for (int i = 0; i < 2; ++i) {
            const int c   = t + 256 * i;    // 0..511
            const int row = c >> 2;         // 0..127
            const int kb  = (c & 3) * 8;    // element offset in k
            const int4 av = *(const int4*)(A  + (size_t)(m0 + row) * KDEPTH + k0 + kb);
            const int4 bv = *(const int4*)(Bp + (size_t)(n0 + row) * KDEPTH + k0 + kb);
            *(int4*)(As + row * 32 + kb) = av;
            *(int4*)(Bs + row * 32 + kb) = bv;
        }
        __syncthreads();

        bf16x8 af[4], bfv[4];
        #pragma unroll
        for (int i = 0; i < 4; ++i) {
            const int ar = wr * 64 + i * 16 + (lane & 15);
            af[i]  = *(const bf16x8*)(As + ar * 32 + (lane >> 4) * 8);
            const int br = wc * 64 + i * 16 + (lane & 15);
            bfv[i] = *(const bf16x8*)(Bs + br * 32 + (lane >> 4) * 8);
        }
        #pragma unroll
        for (int i = 0; i < 4; ++i)
            #pragma unroll
            for (int j = 0; j < 4; ++j)
                acc[i][j] = __builtin_amdgcn_mfma_f32_16x16x32_bf16(
                    af[i], bfv[j], acc[i][j], 0, 0, 0);
        __syncthreads();
    }

    // epilogue: D col = lane&15, row = (lane>>4)*4 + r  [m89-verified]
    #pragma unroll
    for (int i = 0; i < 4; ++i) {
        const int mb = m0 + wr * 64 + i * 16 + (lane >> 4) * 4;
        #pragma unroll
        for (int r = 0; r < 4; ++r) {
            const int m  = mb + r;
            const float bv = bias[m];
            #pragma unroll
            for (int j = 0; j < 4; ++j) {
                const int n = n0 + wc * 64 + j * 16 + (lane & 15);
                Cp[(size_t)m * NPIX + n] = acc[i][j][r] + bv;
            }
        }
    }
}

// ---------------------------------------------------------------------------
// Per (b,h): S[d][e] = SCALE * sum_n q[d,n]*k[e,n]; softmax rows -> attn (fp32)
// ---------------------------------------------------------------------------
__global__ __launch_bounds__(256) void qk_softmax_kernel(
    const float* __restrict__ qkv, float* __restrict__ attn)
{
    const int bh = blockIdx.x;
    const int b = bh >> 3, h = bh & 7;
    const float* qbase = qkv + ((size_t)b * OC3 + h * HDIM) * NPIX;
    const float* kbase = qkv + ((size_t)b * OC3 + CH + h * HDIM) * NPIX;

    __shared__ float qs[64][68];
    __shared__ float ks[64][68];
    __shared__ float ss[64][68];

    const int t  = threadIdx.x;
    const int tx = t & 15, ty = t >> 4;
    const int td = ty * 4, te = tx * 4;

    float acc[4][4] = {};

    for (int nc = 0; nc < 64; ++nc) {
        #pragma unroll
        for (int i = 0; i < 4; ++i) {
            const int lin = t + 256 * i;
            const int row = lin >> 4;
            const int c4  = (lin & 15) * 4;
            const float4 qv = *(const float4*)(qbase + (size_t)row * NPIX + nc * 64 + c4);
            qs[c4 + 0][row] = qv.x; qs[c4 + 1][row] = qv.y;
            qs[c4 + 2][row] = qv.z; qs[c4 + 3][row] = qv.w;
            const float4 kv = *(const float4*)(kbase + (size_t)row * NPIX + nc * 64 + c4);
            ks[c4 + 0][row] = kv.x; ks[c4 + 1][row] = kv.y;
            ks[c4 + 2][row] = kv.z; ks[c4 + 3][row] = kv.w;
        }
        __syncthreads();
        #pragma unroll
        for (int kk = 0; kk < 64; ++kk) {
            const float4 a4 = *(const float4*)&qs[kk][td];
            const float4 b4 = *(const float4*)&ks[kk][te];
            const float a[4]  = {a4.x, a4.y, a4.z, a4.w};
            const float bb[4] = {b4.x, b4.y, b4.z, b4.w};
            #pragma unroll
            for (int i = 0; i < 4; ++i)
                #pragma unroll
                for (int j = 0; j < 4; ++j)
                    acc[i][j] = fmaf(a[i], bb[j], acc[i][j]);
        }
        __syncthreads();
    }

    #pragma unroll
    for (int i = 0; i < 4; ++i)
        #pragma unroll
        for (int j = 0; j < 4; ++j)
            ss[td + i][te + j] = acc[i][j] * SCALE;
    __syncthreads();

    if (t < 64) {
        float m = -1e30f;
        for (int e = 0; e < 64; ++e) m = fmaxf(m, ss[t][e]);
        float s = 0.f;
        for (int e = 0; e < 64; ++e) { const float v = __expf(ss[t][e] - m); ss[t][e] = v; s += v; }
        const float inv = 1.f / s;
        float* arow = attn + ((size_t)bh * 64 + t) * 64;
        for (int e = 0; e < 64; ++e) arow[e] = ss[t][e] * inv;
    }
}

// ---------------------------------------------------------------------------
// attn_mean[b][d][e] = mean_h attn[b][h][d][e]
// ---------------------------------------------------------------------------
__global__ __launch_bounds__(256) void attn_mean_kernel(
    const float* __restrict__ attn, float* __restrict__ om)
{
    const int idx = blockIdx.x * 256 + threadIdx.x;
    const int b = idx >> 12, de = idx & 4095;
    float s = 0.f;
    #pragma unroll
    for (int h = 0; h < 8; ++h)
        s += attn[(((size_t)b * 8 + h) << 12) + de];
    om[idx] = s * 0.125f;
}

// ---------------------------------------------------------------------------
// PV: pvt[b][n][h*64+d] (bf16, n-major) = sum_e attn[b,h,d,e] * v[b][...e][n]
// ---------------------------------------------------------------------------
__global__ __launch_bounds__(256) void pv_kernel(
    const float* __restrict__ attn, const float* __restrict__ qkv,
    bf16* __restrict__ pvt)
{
    const int bh = blockIdx.y;
    const int b = bh >> 3, h = bh & 7;
    const int n = blockIdx.x * 256 + threadIdx.x;

    __shared__ float Asm[4096];
    const float* ab = attn + (size_t)bh * 4096;
    #pragma unroll
    for (int i = 0; i < 4; ++i) {
        const int lin = threadIdx.x + 256 * i;
        *(float4*)&Asm[lin * 4] = *(const float4*)(ab + lin * 4);
    }
    __syncthreads();

    const float* vbase = qkv + ((size_t)b * OC3 + 2 * CH + h * HDIM) * NPIX + n;
    float acc[64];
    #pragma unroll
    for (int d = 0; d < 64; ++d) acc[d] = 0.f;

    for (int e = 0; e < 64; ++e) {
        const float vv = vbase[(size_t)e * NPIX];
        #pragma unroll
        for (int d = 0; d < 64; ++d)
            acc[d] = fmaf(Asm[d * 64 + e], vv, acc[d]);
    }

    bf16* ob = pvt + ((size_t)b * NPIX + n) * CH + h * HDIM;
    #pragma unroll
    for (int d8 = 0; d8 < 8; ++d8) {
        bf16x8 v;
        #pragma unroll
        for (int jj = 0; jj < 8; ++jj) v[jj] = (bf16)acc[d8 * 8 + jj];
        *(bf16x8*)(ob + d8 * 8) = v;
    }
}

// ---------------------------------------------------------------------------
extern "C" void kernel_launch(void* const* d_in, const int* in_sizes, int n_in,
                              void* d_out, int out_size, void* d_ws, size_t ws_size,
                              hipStream_t stream)
{
    (void)in_sizes; (void)n_in; (void)out_size;
    const float* x      = (const float*)d_in[0];
    const float* qkv_w  = (const float*)d_in[1];
    const float* qkv_b  = (const float*)d_in[2];
    const float* proj_w = (const float*)d_in[3];
    const float* proj_b = (const float*)d_in[4];

    float* out       = (float*)d_out;
    float* attn_mean = out + (size_t)BATCH * CH * NPIX;

    // workspace layout
    const size_t qkv_bytes = (size_t)BATCH * OC3 * NPIX * 4;        // 192 MiB
    const size_t xt_bytes  = (size_t)BATCH * NPIX * KDEPTH * 2;     // 32 MiB (also pvt)
    const size_t wq_bytes  = (size_t)OC3 * KDEPTH * 2;              // 1.5 MiB
    const size_t wp_bytes  = (size_t)CH * KDEPTH * 2;               // 0.5 MiB
    const size_t attn_bytes = (size_t)BATCH * HEADS * HDIM * HDIM * 4; // 1 MiB
    const size_t need = qkv_bytes + xt_bytes + wq_bytes + wp_bytes + attn_bytes;
    if (ws_size < need) {
        fprintf(stderr, "[kernel_launch] ws_size=%zu < need=%zu — abort\n", ws_size, need);
        fflush(stderr);
        return;
    }

    char* p = (char*)d_ws;
    float* qkv  = (float*)p;              p += qkv_bytes;
    bf16*  xt   = (bf16*)p;               p += xt_bytes;   // aliased by pvt later
    bf16*  wq_b = (bf16*)p;               p += wq_bytes;
    bf16*  wp_b = (bf16*)p;               p += wp_bytes;
    float* attn = (float*)p;
    bf16*  pvt  = xt;   // xt is dead after the QKV GEMM

    // 0) weight converts
    convert_bf16_kernel<<<dim3((OC3 * KDEPTH + 255) / 256), 256, 0, stream>>>(
        qkv_w, wq_b, OC3 * KDEPTH);
    convert_bf16_kernel<<<dim3((CH * KDEPTH + 255) / 256), 256, 0, stream>>>(
        proj_w, wp_b, CH * KDEPTH);

    // 1) x -> xt (transpose + bf16)
    transpose_convert_kernel<<<dim3(NPIX / 64, KDEPTH / 64, BATCH), 256, 0, stream>>>(x, xt);

    // 2) QKV GEMM (MFMA): qkv = wq_b * xt^T + bias   [fp32 out]
    mfma_gemm_kernel<<<dim3(NPIX / 128, OC3 / 128, BATCH), 256, 0, stream>>>(
        wq_b, xt, qkv_b, qkv, OC3);

    // 3) QK^T + softmax per (b,h)
    qk_softmax_kernel<<<dim3(BATCH * HEADS), 256, 0, stream>>>(qkv, attn);

    // 4) attn mean over heads (output 1)
    attn_mean_kernel<<<dim3(BATCH * HDIM * HDIM / 256), 256, 0, stream>>>(attn, attn_mean);

    // 5) PV -> pvt bf16 n-major (feeds proj GEMM directly)
    pv_kernel<<<dim3(NPIX / 256, BATCH * HEADS), 256, 0, stream>>>(attn, qkv, pvt);

    // 6) proj GEMM (MFMA) -> out fp32
    mfma_gemm_kernel<<<dim3(NPIX / 128, CH / 128, BATCH), 256, 0, stream>>>(
        wp_b, pvt, proj_b, out, CH);
}

// Round 4
// 290.475 us; speedup vs baseline: 3.9298x; 1.4486x over previous
//
#include <hip/hip_runtime.h>
#include <cstdio>
#include <cstdint>

// Problem constants
#define BATCH 8
#define CH    512
#define OC3   1536      // 3*CH
#define NPIX  4096      // 64*64
#define HEADS 8
#define HDIM  64
#define KDEPTH 512      // GEMM K
#define SCALE 0.125f    // 64^-0.5
#define NSPLIT 16       // split-K factor for QK^T (256 n per split)

typedef __bf16 bf16;
typedef __bf16 bf16x8 __attribute__((ext_vector_type(8)));
typedef float  f32x4  __attribute__((ext_vector_type(4)));

// ---------------------------------------------------------------------------
// fp32 -> bf16 flat convert (weights)
// ---------------------------------------------------------------------------
__global__ __launch_bounds__(256) void convert_bf16_kernel(
    const float* __restrict__ in, bf16* __restrict__ out, int n)
{
    const int i = blockIdx.x * 256 + threadIdx.x;
    if (i < n) out[i] = (bf16)in[i];
}

// ---------------------------------------------------------------------------
// x [b][512][4096] fp32  ->  xt [b][4096][512] bf16 (transpose + convert)
// ---------------------------------------------------------------------------
__global__ __launch_bounds__(256) void transpose_convert_kernel(
    const float* __restrict__ x, bf16* __restrict__ xt)
{
    const int b  = blockIdx.z;
    const int n0 = blockIdx.x * 64;
    const int c0 = blockIdx.y * 64;
    __shared__ float tile[64][65];
    const int t = threadIdx.x;
    const float* xp = x + (size_t)b * 512 * 4096;

    #pragma unroll
    for (int i = 0; i < 4; ++i) {
        const int lin = t + 256 * i;
        const int r   = lin >> 4;
        const int c4  = (lin & 15) * 4;
        const float4 v = *(const float4*)(xp + (size_t)(c0 + r) * 4096 + n0 + c4);
        tile[r][c4 + 0] = v.x; tile[r][c4 + 1] = v.y;
        tile[r][c4 + 2] = v.z; tile[r][c4 + 3] = v.w;
    }
    __syncthreads();

    bf16* op = xt + (size_t)b * 4096 * 512;
    #pragma unroll
    for (int i = 0; i < 2; ++i) {
        const int lin = t + 256 * i;
        const int n   = lin >> 3;
        const int c8  = (lin & 7) * 8;
        bf16x8 v;
        #pragma unroll
        for (int jj = 0; jj < 8; ++jj) v[jj] = (bf16)tile[c8 + jj][n];
        *(bf16x8*)(op + (size_t)(n0 + n) * 512 + c0 + c8) = v;
    }
}

// ---------------------------------------------------------------------------
// MFMA GEMM: C[b][m][n] fp32 = sum_k A[m][k] * Bt[b][n][k] + bias[m]
// ---------------------------------------------------------------------------
__global__ __launch_bounds__(256) void mfma_gemm_kernel(
    const bf16* __restrict__ A, const bf16* __restrict__ Bt,
    const float* __restrict__ bias, float* __restrict__ C, int M)
{
    const int b  = blockIdx.z;
    const int m0 = blockIdx.y * 128;
    const int n0 = blockIdx.x * 128;
    const bf16* Bp = Bt + (size_t)b * NPIX * KDEPTH;
    float* Cp      = C  + (size_t)b * M * NPIX;

    __shared__ bf16 As[128 * 32];
    __shared__ bf16 Bs[128 * 32];

    const int t    = threadIdx.x;
    const int lane = t & 63;
    const int wave = t >> 6;
    const int wr   = wave >> 1, wc = wave & 1;

    f32x4 acc[4][4];
    const f32x4 zf = {0.f, 0.f, 0.f, 0.f};
    #pragma unroll
    for (int i = 0; i < 4; ++i)
        #pragma unroll
        for (int j = 0; j < 4; ++j) acc[i][j] = zf;

    for (int k0 = 0; k0 < KDEPTH; k0 += 32) {
        #pragma unroll
        for (int i = 0; i < 2; ++i) {
            const int c   = t + 256 * i;
            const int row = c >> 2;
            const int kb  = (c & 3) * 8;
            const int4 av = *(const int4*)(A  + (size_t)(m0 + row) * KDEPTH + k0 + kb);
            const int4 bv = *(const int4*)(Bp + (size_t)(n0 + row) * KDEPTH + k0 + kb);
            *(int4*)(As + row * 32 + kb) = av;
            *(int4*)(Bs + row * 32 + kb) = bv;
        }
        __syncthreads();

        bf16x8 af[4], bfv[4];
        #pragma unroll
        for (int i = 0; i < 4; ++i) {
            const int ar = wr * 64 + i * 16 + (lane & 15);
            af[i]  = *(const bf16x8*)(As + ar * 32 + (lane >> 4) * 8);
            const int br = wc * 64 + i * 16 + (lane & 15);
            bfv[i] = *(const bf16x8*)(Bs + br * 32 + (lane >> 4) * 8);
        }
        #pragma unroll
        for (int i = 0; i < 4; ++i)
            #pragma unroll
            for (int j = 0; j < 4; ++j)
                acc[i][j] = __builtin_amdgcn_mfma_f32_16x16x32_bf16(
                    af[i], bfv[j], acc[i][j], 0, 0, 0);
        __syncthreads();
    }

    #pragma unroll
    for (int i = 0; i < 4; ++i) {
        const int mb = m0 + wr * 64 + i * 16 + (lane >> 4) * 4;
        #pragma unroll
        for (int r = 0; r < 4; ++r) {
            const int m  = mb + r;
            const float bv = bias[m];
            #pragma unroll
            for (int j = 0; j < 4; ++j) {
                const int n = n0 + wc * 64 + j * 16 + (lane & 15);
                Cp[(size_t)m * NPIX + n] = acc[i][j][r] + bv;
            }
        }
    }
}

// ---------------------------------------------------------------------------
// QK^T split-K partial: part[bh][s][d][e] = sum_{n in split s} q[d,n]*k[e,n]
// grid (NSPLIT, 64). 256 thr. LDS float4 tiles, slot XOR-swizzled by row&15.
// Thread (tx,ty): rows d = ty+16i, cols e = tx+16j  (i,j = 0..3).
// ---------------------------------------------------------------------------
__global__ __launch_bounds__(256) void qk_partial_kernel(
    const float* __restrict__ qkv, float* __restrict__ part)
{
    const int s  = blockIdx.x;
    const int bh = blockIdx.y;
    const int b = bh >> 3, h = bh & 7;
    const float* qbase = qkv + ((size_t)b * OC3 + h * HDIM) * NPIX;
    const float* kbase = qkv + ((size_t)b * OC3 + CH + h * HDIM) * NPIX;

    __shared__ f32x4 qs4[64 * 16];
    __shared__ f32x4 ks4[64 * 16];

    const int t  = threadIdx.x;
    const int tx = t & 15, ty = t >> 4;

    float acc[4][4] = {};

    for (int nc = 0; nc < 4; ++nc) {
        const int n0 = s * 256 + nc * 64;
        #pragma unroll
        for (int i = 0; i < 4; ++i) {
            const int lin = t + 256 * i;        // 0..1023
            const int row = lin >> 4;           // 0..63
            const int sl  = lin & 15;           // float4 slot
            qs4[row * 16 + (sl ^ (row & 15))] =
                *(const f32x4*)(qbase + (size_t)row * NPIX + n0 + sl * 4);
            ks4[row * 16 + (sl ^ (row & 15))] =
                *(const f32x4*)(kbase + (size_t)row * NPIX + n0 + sl * 4);
        }
        __syncthreads();

        #pragma unroll
        for (int kk4 = 0; kk4 < 16; ++kk4) {
            f32x4 qf[4], kf[4];
            #pragma unroll
            for (int i = 0; i < 4; ++i)
                qf[i] = qs4[(ty + 16 * i) * 16 + (kk4 ^ ty)];
            #pragma unroll
            for (int j = 0; j < 4; ++j)
                kf[j] = ks4[(tx + 16 * j) * 16 + (kk4 ^ tx)];
            #pragma unroll
            for (int i = 0; i < 4; ++i)
                #pragma unroll
                for (int j = 0; j < 4; ++j) {
                    acc[i][j] = fmaf(qf[i][0], kf[j][0], acc[i][j]);
                    acc[i][j] = fmaf(qf[i][1], kf[j][1], acc[i][j]);
                    acc[i][j] = fmaf(qf[i][2], kf[j][2], acc[i][j]);
                    acc[i][j] = fmaf(qf[i][3], kf[j][3], acc[i][j]);
                }
        }
        __syncthreads();
    }

    float* pb = part + (((size_t)bh * NSPLIT + s) * 64) * 64;
    #pragma unroll
    for (int i = 0; i < 4; ++i)
        #pragma unroll
        for (int j = 0; j < 4; ++j)
            pb[(ty + 16 * i) * 64 + tx + 16 * j] = acc[i][j];
}

// ---------------------------------------------------------------------------
// Reduce partials + row softmax -> attn[bh][d][e] (fp32)
// 64 blocks, 256 thr: thread t -> row r=t>>2, 16 cols at (t&3)*16.
// ---------------------------------------------------------------------------
__global__ __launch_bounds__(256) void qk_reduce_softmax_kernel(
    const float* __restrict__ part, float* __restrict__ attn)
{
    const int bh = blockIdx.x;
    const int t  = threadIdx.x;
    const int r  = t >> 2;
    const int e0 = (t & 3) * 16;

    float v[16];
    #pragma unroll
    for (int i = 0; i < 16; ++i) v[i] = 0.f;

    const float* pb = part + ((size_t)bh * NSPLIT * 64) * 64 + r * 64 + e0;
    for (int s = 0; s < NSPLIT; ++s) {
        const float* ps = pb + (size_t)s * 4096;
        #pragma unroll
        for (int c4 = 0; c4 < 4; ++c4) {
            const float4 p = *(const float4*)(ps + c4 * 4);
            v[c4 * 4 + 0] += p.x; v[c4 * 4 + 1] += p.y;
            v[c4 * 4 + 2] += p.z; v[c4 * 4 + 3] += p.w;
        }
    }

    float m = -1e30f;
    #pragma unroll
    for (int i = 0; i < 16; ++i) m = fmaxf(m, v[i]);
    m = fmaxf(m, __shfl_xor(m, 1));
    m = fmaxf(m, __shfl_xor(m, 2));

    float sum = 0.f;
    #pragma unroll
    for (int i = 0; i < 16; ++i) {
        v[i] = __expf((v[i] - m) * SCALE);
        sum += v[i];
    }
    sum += __shfl_xor(sum, 1);
    sum += __shfl_xor(sum, 2);
    const float inv = 1.f / sum;

    float* arow = attn + ((size_t)bh * 64 + r) * 64 + e0;
    #pragma unroll
    for (int c4 = 0; c4 < 4; ++c4) {
        float4 o;
        o.x = v[c4 * 4 + 0] * inv; o.y = v[c4 * 4 + 1] * inv;
        o.z = v[c4 * 4 + 2] * inv; o.w = v[c4 * 4 + 3] * inv;
        *(float4*)(arow + c4 * 4) = o;
    }
}

// ---------------------------------------------------------------------------
// attn_mean[b][d][e] = mean_h attn[b][h][d][e]
// ---------------------------------------------------------------------------
__global__ __launch_bounds__(256) void attn_mean_kernel(
    const float* __restrict__ attn, float* __restrict__ om)
{
    const int idx = blockIdx.x * 256 + threadIdx.x;
    const int b = idx >> 12, de = idx & 4095;
    float s = 0.f;
    #pragma unroll
    for (int h = 0; h < 8; ++h)
        s += attn[(((size_t)b * 8 + h) << 12) + de];
    om[idx] = s * 0.125f;
}

// ---------------------------------------------------------------------------
// PV: pvt[b][n][h*64+d] (bf16, n-major) = sum_e attn[b,h,d,e] * v[b][...e][n]
// ---------------------------------------------------------------------------
__global__ __launch_bounds__(256) void pv_kernel(
    const float* __restrict__ attn, const float* __restrict__ qkv,
    bf16* __restrict__ pvt)
{
    const int bh = blockIdx.y;
    const int b = bh >> 3, h = bh & 7;
    const int n = blockIdx.x * 256 + threadIdx.x;

    __shared__ float Asm[4096];
    const float* ab = attn + (size_t)bh * 4096;
    #pragma unroll
    for (int i = 0; i < 4; ++i) {
        const int lin = threadIdx.x + 256 * i;
        *(float4*)&Asm[lin * 4] = *(const float4*)(ab + lin * 4);
    }
    __syncthreads();

    const float* vbase = qkv + ((size_t)b * OC3 + 2 * CH + h * HDIM) * NPIX + n;
    float acc[64];
    #pragma unroll
    for (int d = 0; d < 64; ++d) acc[d] = 0.f;

    for (int e = 0; e < 64; ++e) {
        const float vv = vbase[(size_t)e * NPIX];
        #pragma unroll
        for (int d = 0; d < 64; ++d)
            acc[d] = fmaf(Asm[d * 64 + e], vv, acc[d]);
    }

    bf16* ob = pvt + ((size_t)b * NPIX + n) * CH + h * HDIM;
    #pragma unroll
    for (int d8 = 0; d8 < 8; ++d8) {
        bf16x8 v;
        #pragma unroll
        for (int jj = 0; jj < 8; ++jj) v[jj] = (bf16)acc[d8 * 8 + jj];
        *(bf16x8*)(ob + d8 * 8) = v;
    }
}

// ---------------------------------------------------------------------------
extern "C" void kernel_launch(void* const* d_in, const int* in_sizes, int n_in,
                              void* d_out, int out_size, void* d_ws, size_t ws_size,
                              hipStream_t stream)
{
    (void)in_sizes; (void)n_in; (void)out_size;
    const float* x      = (const float*)d_in[0];
    const float* qkv_w  = (const float*)d_in[1];
    const float* qkv_b  = (const float*)d_in[2];
    const float* proj_w = (const float*)d_in[3];
    const float* proj_b = (const float*)d_in[4];

    float* out       = (float*)d_out;
    float* attn_mean = out + (size_t)BATCH * CH * NPIX;

    const size_t qkv_bytes  = (size_t)BATCH * OC3 * NPIX * 4;          // 192 MiB
    const size_t xt_bytes   = (size_t)BATCH * NPIX * KDEPTH * 2;       //  32 MiB
    const size_t wq_bytes   = (size_t)OC3 * KDEPTH * 2;                // 1.5 MiB
    const size_t wp_bytes   = (size_t)CH * KDEPTH * 2;                 // 0.5 MiB
    const size_t attn_bytes = (size_t)BATCH * HEADS * HDIM * HDIM * 4; //   1 MiB
    const size_t part_bytes = (size_t)BATCH * HEADS * NSPLIT * HDIM * HDIM * 4; // 16 MiB
    const size_t need = qkv_bytes + xt_bytes + wq_bytes + wp_bytes + attn_bytes + part_bytes;
    if (ws_size < need) {
        fprintf(stderr, "[kernel_launch] ws_size=%zu < need=%zu — abort\n", ws_size, need);
        fflush(stderr);
        return;
    }

    char* p = (char*)d_ws;
    float* qkv  = (float*)p;              p += qkv_bytes;
    bf16*  xt   = (bf16*)p;               p += xt_bytes;
    bf16*  wq_b = (bf16*)p;               p += wq_bytes;
    bf16*  wp_b = (bf16*)p;               p += wp_bytes;
    float* attn = (float*)p;              p += attn_bytes;
    float* part = (float*)p;
    bf16*  pvt  = xt;   // xt is dead after the QKV GEMM

    convert_bf16_kernel<<<dim3((OC3 * KDEPTH + 255) / 256), 256, 0, stream>>>(
        qkv_w, wq_b, OC3 * KDEPTH);
    convert_bf16_kernel<<<dim3((CH * KDEPTH + 255) / 256), 256, 0, stream>>>(
        proj_w, wp_b, CH * KDEPTH);

    transpose_convert_kernel<<<dim3(NPIX / 64, KDEPTH / 64, BATCH), 256, 0, stream>>>(x, xt);

    mfma_gemm_kernel<<<dim3(NPIX / 128, OC3 / 128, BATCH), 256, 0, stream>>>(
        wq_b, xt, qkv_b, qkv, OC3);

    qk_partial_kernel<<<dim3(NSPLIT, BATCH * HEADS), 256, 0, stream>>>(qkv, part);
    qk_reduce_softmax_kernel<<<dim3(BATCH * HEADS), 256, 0, stream>>>(part, attn);

    attn_mean_kernel<<<dim3(BATCH * HDIM * HDIM / 256), 256, 0, stream>>>(attn, attn_mean);

    pv_kernel<<<dim3(NPIX / 256, BATCH * HEADS), 256, 0, stream>>>(attn, qkv, pvt);

    mfma_gemm_kernel<<<dim3(NPIX / 128, CH / 128, BATCH), 256, 0, stream>>>(
        wp_b, pvt, proj_b, out, CH);
}

// Round 5
// 270.507 us; speedup vs baseline: 4.2199x; 1.0738x over previous
//
#include <hip/hip_runtime.h>
#include <cstdio>
#include <cstdint>

// Problem constants
#define BATCH 8
#define CH    512
#define OC3   1536      // 3*CH
#define NPIX  4096      // 64*64
#define HEADS 8
#define HDIM  64
#define KDEPTH 512      // GEMM K
#define SCALE 0.125f    // 64^-0.5
#define NSPLIT 16       // split-K factor for QK^T (256 n per split)

typedef __bf16 bf16;
typedef __bf16 bf16x8 __attribute__((ext_vector_type(8)));
typedef float  f32x4  __attribute__((ext_vector_type(4)));

// ---------------------------------------------------------------------------
// fp32 -> bf16 flat convert (weights)
// ---------------------------------------------------------------------------
__global__ __launch_bounds__(256) void convert_bf16_kernel(
    const float* __restrict__ in, bf16* __restrict__ out, int n)
{
    const int i = blockIdx.x * 256 + threadIdx.x;
    if (i < n) out[i] = (bf16)in[i];
}

// ---------------------------------------------------------------------------
// x [b][512][4096] fp32  ->  xt [b][4096][512] bf16 (transpose + convert)
// ---------------------------------------------------------------------------
__global__ __launch_bounds__(256) void transpose_convert_kernel(
    const float* __restrict__ x, bf16* __restrict__ xt)
{
    const int b  = blockIdx.z;
    const int n0 = blockIdx.x * 64;
    const int c0 = blockIdx.y * 64;
    __shared__ float tile[64][65];
    const int t = threadIdx.x;
    const float* xp = x + (size_t)b * 512 * 4096;

    #pragma unroll
    for (int i = 0; i < 4; ++i) {
        const int lin = t + 256 * i;
        const int r   = lin >> 4;
        const int c4  = (lin & 15) * 4;
        const float4 v = *(const float4*)(xp + (size_t)(c0 + r) * 4096 + n0 + c4);
        tile[r][c4 + 0] = v.x; tile[r][c4 + 1] = v.y;
        tile[r][c4 + 2] = v.z; tile[r][c4 + 3] = v.w;
    }
    __syncthreads();

    bf16* op = xt + (size_t)b * 4096 * 512;
    #pragma unroll
    for (int i = 0; i < 2; ++i) {
        const int lin = t + 256 * i;
        const int n   = lin >> 3;
        const int c8  = (lin & 7) * 8;
        bf16x8 v;
        #pragma unroll
        for (int jj = 0; jj < 8; ++jj) v[jj] = (bf16)tile[c8 + jj][n];
        *(bf16x8*)(op + (size_t)(n0 + n) * 512 + c0 + c8) = v;
    }
}

// ---------------------------------------------------------------------------
// MFMA GEMM: C[b][m][n] fp32 = sum_k A[m][k] * Bt[b][n][k] + bias[m]
// A: [M][512] bf16, Bt: [b][4096][512] bf16. 128x128 tile, BK=32,
// 256 thr = 4 waves (2x2), each wave 64x64 via 4x4 frags of 16x16x32.
// Staging via global_load_lds width=16 (m97 structure): LDS linear in
// thread order -> per-wave dest = uniform base + lane*16 (HW constraint).
// ---------------------------------------------------------------------------
__global__ __launch_bounds__(256) void mfma_gemm_kernel(
    const bf16* __restrict__ A, const bf16* __restrict__ Bt,
    const float* __restrict__ bias, float* __restrict__ C, int M)
{
    const int b  = blockIdx.z;
    const int m0 = blockIdx.y * 128;
    const int n0 = blockIdx.x * 128;
    const bf16* Bp = Bt + (size_t)b * NPIX * KDEPTH;
    float* Cp      = C  + (size_t)b * M * NPIX;

    __shared__ bf16 As[128 * 32];
    __shared__ bf16 Bs[128 * 32];

    const int t    = threadIdx.x;
    const int lane = t & 63;
    const int wave = t >> 6;
    const int wr   = wave >> 1, wc = wave & 1;

    f32x4 acc[4][4];
    const f32x4 zf = {0.f, 0.f, 0.f, 0.f};
    #pragma unroll
    for (int i = 0; i < 4; ++i)
        #pragma unroll
        for (int j = 0; j < 4; ++j) acc[i][j] = zf;

    for (int k0 = 0; k0 < KDEPTH; k0 += 32) {
        // async global -> LDS staging, 16B per lane per issue
        #pragma unroll
        for (int i = 0; i < 2; ++i) {
            const int c   = t + 256 * i;    // 0..511 16B-chunks
            const int row = c >> 2;         // 0..127
            const int kb  = (c & 3) * 8;    // k element offset
            __builtin_amdgcn_global_load_lds(
                (const __attribute__((address_space(1))) void*)(A + (size_t)(m0 + row) * KDEPTH + k0 + kb),
                (__attribute__((address_space(3))) void*)(As + c * 8), 16, 0, 0);
            __builtin_amdgcn_global_load_lds(
                (const __attribute__((address_space(1))) void*)(Bp + (size_t)(n0 + row) * KDEPTH + k0 + kb),
                (__attribute__((address_space(3))) void*)(Bs + c * 8), 16, 0, 0);
        }
        __syncthreads();

        bf16x8 af[4], bfv[4];
        #pragma unroll
        for (int i = 0; i < 4; ++i) {
            const int ar = wr * 64 + i * 16 + (lane & 15);
            af[i]  = *(const bf16x8*)(As + ar * 32 + (lane >> 4) * 8);
            const int br = wc * 64 + i * 16 + (lane & 15);
            bfv[i] = *(const bf16x8*)(Bs + br * 32 + (lane >> 4) * 8);
        }
        #pragma unroll
        for (int i = 0; i < 4; ++i)
            #pragma unroll
            for (int j = 0; j < 4; ++j)
                acc[i][j] = __builtin_amdgcn_mfma_f32_16x16x32_bf16(
                    af[i], bfv[j], acc[i][j], 0, 0, 0);
        __syncthreads();
    }

    #pragma unroll
    for (int i = 0; i < 4; ++i) {
        const int mb = m0 + wr * 64 + i * 16 + (lane >> 4) * 4;
        #pragma unroll
        for (int r = 0; r < 4; ++r) {
            const int m  = mb + r;
            const float bv = bias[m];
            #pragma unroll
            for (int j = 0; j < 4; ++j) {
                const int n = n0 + wc * 64 + j * 16 + (lane & 15);
                Cp[(size_t)m * NPIX + n] = acc[i][j][r] + bv;
            }
        }
    }
}

// ---------------------------------------------------------------------------
// QK^T split-K partial: part[bh][s][d][e] = sum_{n in split s} q[d,n]*k[e,n]
// ---------------------------------------------------------------------------
__global__ __launch_bounds__(256) void qk_partial_kernel(
    const float* __restrict__ qkv, float* __restrict__ part)
{
    const int s  = blockIdx.x;
    const int bh = blockIdx.y;
    const int b = bh >> 3, h = bh & 7;
    const float* qbase = qkv + ((size_t)b * OC3 + h * HDIM) * NPIX;
    const float* kbase = qkv + ((size_t)b * OC3 + CH + h * HDIM) * NPIX;

    __shared__ f32x4 qs4[64 * 16];
    __shared__ f32x4 ks4[64 * 16];

    const int t  = threadIdx.x;
    const int tx = t & 15, ty = t >> 4;

    float acc[4][4] = {};

    for (int nc = 0; nc < 4; ++nc) {
        const int n0 = s * 256 + nc * 64;
        #pragma unroll
        for (int i = 0; i < 4; ++i) {
            const int lin = t + 256 * i;        // 0..1023
            const int row = lin >> 4;           // 0..63
            const int sl  = lin & 15;           // float4 slot
            qs4[row * 16 + (sl ^ (row & 15))] =
                *(const f32x4*)(qbase + (size_t)row * NPIX + n0 + sl * 4);
            ks4[row * 16 + (sl ^ (row & 15))] =
                *(const f32x4*)(kbase + (size_t)row * NPIX + n0 + sl * 4);
        }
        __syncthreads();

        #pragma unroll
        for (int kk4 = 0; kk4 < 16; ++kk4) {
            f32x4 qf[4], kf[4];
            #pragma unroll
            for (int i = 0; i < 4; ++i)
                qf[i] = qs4[(ty + 16 * i) * 16 + (kk4 ^ ty)];
            #pragma unroll
            for (int j = 0; j < 4; ++j)
                kf[j] = ks4[(tx + 16 * j) * 16 + (kk4 ^ tx)];
            #pragma unroll
            for (int i = 0; i < 4; ++i)
                #pragma unroll
                for (int j = 0; j < 4; ++j) {
                    acc[i][j] = fmaf(qf[i][0], kf[j][0], acc[i][j]);
                    acc[i][j] = fmaf(qf[i][1], kf[j][1], acc[i][j]);
                    acc[i][j] = fmaf(qf[i][2], kf[j][2], acc[i][j]);
                    acc[i][j] = fmaf(qf[i][3], kf[j][3], acc[i][j]);
                }
        }
        __syncthreads();
    }

    float* pb = part + (((size_t)bh * NSPLIT + s) * 64) * 64;
    #pragma unroll
    for (int i = 0; i < 4; ++i)
        #pragma unroll
        for (int j = 0; j < 4; ++j)
            pb[(ty + 16 * i) * 64 + tx + 16 * j] = acc[i][j];
}

// ---------------------------------------------------------------------------
// Reduce partials + row softmax -> attn[bh][d][e] (fp32)
// ---------------------------------------------------------------------------
__global__ __launch_bounds__(256) void qk_reduce_softmax_kernel(
    const float* __restrict__ part, float* __restrict__ attn)
{
    const int bh = blockIdx.x;
    const int t  = threadIdx.x;
    const int r  = t >> 2;
    const int e0 = (t & 3) * 16;

    float v[16];
    #pragma unroll
    for (int i = 0; i < 16; ++i) v[i] = 0.f;

    const float* pb = part + ((size_t)bh * NSPLIT * 64) * 64 + r * 64 + e0;
    for (int s = 0; s < NSPLIT; ++s) {
        const float* ps = pb + (size_t)s * 4096;
        #pragma unroll
        for (int c4 = 0; c4 < 4; ++c4) {
            const float4 p = *(const float4*)(ps + c4 * 4);
            v[c4 * 4 + 0] += p.x; v[c4 * 4 + 1] += p.y;
            v[c4 * 4 + 2] += p.z; v[c4 * 4 + 3] += p.w;
        }
    }

    float m = -1e30f;
    #pragma unroll
    for (int i = 0; i < 16; ++i) m = fmaxf(m, v[i]);
    m = fmaxf(m, __shfl_xor(m, 1));
    m = fmaxf(m, __shfl_xor(m, 2));

    float sum = 0.f;
    #pragma unroll
    for (int i = 0; i < 16; ++i) {
        v[i] = __expf((v[i] - m) * SCALE);
        sum += v[i];
    }
    sum += __shfl_xor(sum, 1);
    sum += __shfl_xor(sum, 2);
    const float inv = 1.f / sum;

    float* arow = attn + ((size_t)bh * 64 + r) * 64 + e0;
    #pragma unroll
    for (int c4 = 0; c4 < 4; ++c4) {
        float4 o;
        o.x = v[c4 * 4 + 0] * inv; o.y = v[c4 * 4 + 1] * inv;
        o.z = v[c4 * 4 + 2] * inv; o.w = v[c4 * 4 + 3] * inv;
        *(float4*)(arow + c4 * 4) = o;
    }
}

// ---------------------------------------------------------------------------
// attn_mean[b][d][e] = mean_h attn[b][h][d][e]
// ---------------------------------------------------------------------------
__global__ __launch_bounds__(256) void attn_mean_kernel(
    const float* __restrict__ attn, float* __restrict__ om)
{
    const int idx = blockIdx.x * 256 + threadIdx.x;
    const int b = idx >> 12, de = idx & 4095;
    float s = 0.f;
    #pragma unroll
    for (int h = 0; h < 8; ++h)
        s += attn[(((size_t)b * 8 + h) << 12) + de];
    om[idx] = s * 0.125f;
}

// ---------------------------------------------------------------------------
// PV: pvt[b][n][h*64+d] (bf16, n-major) = sum_e attn[b,h,d,e] * v[b][...e][n]
// ---------------------------------------------------------------------------
__global__ __launch_bounds__(256) void pv_kernel(
    const float* __restrict__ attn, const float* __restrict__ qkv,
    bf16* __restrict__ pvt)
{
    const int bh = blockIdx.y;
    const int b = bh >> 3, h = bh & 7;
    const int n = blockIdx.x * 256 + threadIdx.x;

    __shared__ float Asm[4096];
    const float* ab = attn + (size_t)bh * 4096;
    #pragma unroll
    for (int i = 0; i < 4; ++i) {
        const int lin = threadIdx.x + 256 * i;
        *(float4*)&Asm[lin * 4] = *(const float4*)(ab + lin * 4);
    }
    __syncthreads();

    const float* vbase = qkv + ((size_t)b * OC3 + 2 * CH + h * HDIM) * NPIX + n;
    float acc[64];
    #pragma unroll
    for (int d = 0; d < 64; ++d) acc[d] = 0.f;

    for (int e = 0; e < 64; ++e) {
        const float vv = vbase[(size_t)e * NPIX];
        #pragma unroll
        for (int d = 0; d < 64; ++d)
            acc[d] = fmaf(Asm[d * 64 + e], vv, acc[d]);
    }

    bf16* ob = pvt + ((size_t)b * NPIX + n) * CH + h * HDIM;
    #pragma unroll
    for (int d8 = 0; d8 < 8; ++d8) {
        bf16x8 v;
        #pragma unroll
        for (int jj = 0; jj < 8; ++jj) v[jj] = (bf16)acc[d8 * 8 + jj];
        *(bf16x8*)(ob + d8 * 8) = v;
    }
}

// ---------------------------------------------------------------------------
extern "C" void kernel_launch(void* const* d_in, const int* in_sizes, int n_in,
                              void* d_out, int out_size, void* d_ws, size_t ws_size,
                              hipStream_t stream)
{
    (void)in_sizes; (void)n_in; (void)out_size;
    const float* x      = (const float*)d_in[0];
    const float* qkv_w  = (const float*)d_in[1];
    const float* qkv_b  = (const float*)d_in[2];
    const float* proj_w = (const float*)d_in[3];
    const float* proj_b = (const float*)d_in[4];

    float* out       = (float*)d_out;
    float* attn_mean = out + (size_t)BATCH * CH * NPIX;

    const size_t qkv_bytes  = (size_t)BATCH * OC3 * NPIX * 4;          // 192 MiB
    const size_t xt_bytes   = (size_t)BATCH * NPIX * KDEPTH * 2;       //  32 MiB
    const size_t wq_bytes   = (size_t)OC3 * KDEPTH * 2;                // 1.5 MiB
    const size_t wp_bytes   = (size_t)CH * KDEPTH * 2;                 // 0.5 MiB
    const size_t attn_bytes = (size_t)BATCH * HEADS * HDIM * HDIM * 4; //   1 MiB
    const size_t part_bytes = (size_t)BATCH * HEADS * NSPLIT * HDIM * HDIM * 4; // 16 MiB
    const size_t need = qkv_bytes + xt_bytes + wq_bytes + wp_bytes + attn_bytes + part_bytes;
    if (ws_size < need) {
        fprintf(stderr, "[kernel_launch] ws_size=%zu < need=%zu — abort\n", ws_size, need);
        fflush(stderr);
        return;
    }

    char* p = (char*)d_ws;
    float* qkv  = (float*)p;              p += qkv_bytes;
    bf16*  xt   = (bf16*)p;               p += xt_bytes;
    bf16*  wq_b = (bf16*)p;               p += wq_bytes;
    bf16*  wp_b = (bf16*)p;               p += wp_bytes;
    float* attn = (float*)p;              p += attn_bytes;
    float* part = (float*)p;
    bf16*  pvt  = xt;   // xt is dead after the QKV GEMM

    convert_bf16_kernel<<<dim3((OC3 * KDEPTH + 255) / 256), 256, 0, stream>>>(
        qkv_w, wq_b, OC3 * KDEPTH);
    convert_bf16_kernel<<<dim3((CH * KDEPTH + 255) / 256), 256, 0, stream>>>(
        proj_w, wp_b, CH * KDEPTH);

    transpose_convert_kernel<<<dim3(NPIX / 64, KDEPTH / 64, BATCH), 256, 0, stream>>>(x, xt);

    mfma_gemm_kernel<<<dim3(NPIX / 128, OC3 / 128, BATCH), 256, 0, stream>>>(
        wq_b, xt, qkv_b, qkv, OC3);

    qk_partial_kernel<<<dim3(NSPLIT, BATCH * HEADS), 256, 0, stream>>>(qkv, part);
    qk_reduce_softmax_kernel<<<dim3(BATCH * HEADS), 256, 0, stream>>>(part, attn);

    attn_mean_kernel<<<dim3(BATCH * HDIM * HDIM / 256), 256, 0, stream>>>(attn, attn_mean);

    pv_kernel<<<dim3(NPIX / 256, BATCH * HEADS), 256, 0, stream>>>(attn, qkv, pvt);

    mfma_gemm_kernel<<<dim3(NPIX / 128, CH / 128, BATCH), 256, 0, stream>>>(
        wp_b, pvt, proj_b, out, CH);
}

// Round 6
// 215.716 us; speedup vs baseline: 5.2917x; 1.2540x over previous
//
#include <hip/hip_runtime.h>
#include <cstdio>
#include <cstdint>

// Problem constants
#define BATCH 8
#define CH    512
#define OC3   1536      // 3*CH
#define NPIX  4096      // 64*64
#define HEADS 8
#define HDIM  64
#define KDEPTH 512      // GEMM K
#define SCALE 0.125f    // 64^-0.5
#define NSPLIT 16       // split-K factor for QK^T (256 n per split)

typedef __bf16 bf16;
typedef __bf16 bf16x8 __attribute__((ext_vector_type(8)));
typedef float  f32x4  __attribute__((ext_vector_type(4)));

// ---------------------------------------------------------------------------
// fp32 -> bf16 flat convert (weights)
// ---------------------------------------------------------------------------
__global__ __launch_bounds__(256) void convert_bf16_kernel(
    const float* __restrict__ in, bf16* __restrict__ out, int n)
{
    const int i = blockIdx.x * 256 + threadIdx.x;
    if (i < n) out[i] = (bf16)in[i];
}

// ---------------------------------------------------------------------------
// src [b][512][4096] fp32 (row stride 4096, batch stride src_bstride)
//   -> dst [b][4096][512] bf16 (transpose + convert)
// Used for x -> xt and for V-region-of-qkv -> vt.
// ---------------------------------------------------------------------------
__global__ __launch_bounds__(256) void transpose_convert_kernel(
    const float* __restrict__ src, bf16* __restrict__ dst, size_t src_bstride)
{
    const int b  = blockIdx.z;
    const int n0 = blockIdx.x * 64;
    const int c0 = blockIdx.y * 64;
    __shared__ float tile[64][65];
    const int t = threadIdx.x;
    const float* xp = src + (size_t)b * src_bstride;

    #pragma unroll
    for (int i = 0; i < 4; ++i) {
        const int lin = t + 256 * i;
        const int r   = lin >> 4;
        const int c4  = (lin & 15) * 4;
        const float4 v = *(const float4*)(xp + (size_t)(c0 + r) * 4096 + n0 + c4);
        tile[r][c4 + 0] = v.x; tile[r][c4 + 1] = v.y;
        tile[r][c4 + 2] = v.z; tile[r][c4 + 3] = v.w;
    }
    __syncthreads();

    bf16* op = dst + (size_t)b * 4096 * 512;
    #pragma unroll
    for (int i = 0; i < 2; ++i) {
        const int lin = t + 256 * i;
        const int n   = lin >> 3;
        const int c8  = (lin & 7) * 8;
        bf16x8 v;
        #pragma unroll
        for (int jj = 0; jj < 8; ++jj) v[jj] = (bf16)tile[c8 + jj][n];
        *(bf16x8*)(op + (size_t)(n0 + n) * 512 + c0 + c8) = v;
    }
}

// ---------------------------------------------------------------------------
// MFMA GEMM: C[b][m][n] fp32 = sum_k A[b][m][k] * Bt[b][n][k] + bias[m]
// A: [M][512] bf16 (per-batch if a_bstride != 0). 128x128 tile, BK=32,
// 256 thr = 4 waves (2x2). Staging via global_load_lds width=16.
// ---------------------------------------------------------------------------
__global__ __launch_bounds__(256) void mfma_gemm_kernel(
    const bf16* __restrict__ A, const bf16* __restrict__ Bt,
    const float* __restrict__ bias, float* __restrict__ C,
    int M, size_t a_bstride)
{
    const int b  = blockIdx.z;
    const int m0 = blockIdx.y * 128;
    const int n0 = blockIdx.x * 128;
    const bf16* Ap = A  + (size_t)b * a_bstride;
    const bf16* Bp = Bt + (size_t)b * NPIX * KDEPTH;
    float* Cp      = C  + (size_t)b * M * NPIX;

    __shared__ bf16 As[128 * 32];
    __shared__ bf16 Bs[128 * 32];

    const int t    = threadIdx.x;
    const int lane = t & 63;
    const int wave = t >> 6;
    const int wr   = wave >> 1, wc = wave & 1;

    f32x4 acc[4][4];
    const f32x4 zf = {0.f, 0.f, 0.f, 0.f};
    #pragma unroll
    for (int i = 0; i < 4; ++i)
        #pragma unroll
        for (int j = 0; j < 4; ++j) acc[i][j] = zf;

    for (int k0 = 0; k0 < KDEPTH; k0 += 32) {
        #pragma unroll
        for (int i = 0; i < 2; ++i) {
            const int c   = t + 256 * i;    // 0..511 16B-chunks
            const int row = c >> 2;         // 0..127
            const int kb  = (c & 3) * 8;    // k element offset
            __builtin_amdgcn_global_load_lds(
                (const __attribute__((address_space(1))) void*)(Ap + (size_t)(m0 + row) * KDEPTH + k0 + kb),
                (__attribute__((address_space(3))) void*)(As + c * 8), 16, 0, 0);
            __builtin_amdgcn_global_load_lds(
                (const __attribute__((address_space(1))) void*)(Bp + (size_t)(n0 + row) * KDEPTH + k0 + kb),
                (__attribute__((address_space(3))) void*)(Bs + c * 8), 16, 0, 0);
        }
        __syncthreads();

        bf16x8 af[4], bfv[4];
        #pragma unroll
        for (int i = 0; i < 4; ++i) {
            const int ar = wr * 64 + i * 16 + (lane & 15);
            af[i]  = *(const bf16x8*)(As + ar * 32 + (lane >> 4) * 8);
            const int br = wc * 64 + i * 16 + (lane & 15);
            bfv[i] = *(const bf16x8*)(Bs + br * 32 + (lane >> 4) * 8);
        }
        #pragma unroll
        for (int i = 0; i < 4; ++i)
            #pragma unroll
            for (int j = 0; j < 4; ++j)
                acc[i][j] = __builtin_amdgcn_mfma_f32_16x16x32_bf16(
                    af[i], bfv[j], acc[i][j], 0, 0, 0);
        __syncthreads();
    }

    #pragma unroll
    for (int i = 0; i < 4; ++i) {
        const int mb = m0 + wr * 64 + i * 16 + (lane >> 4) * 4;
        #pragma unroll
        for (int r = 0; r < 4; ++r) {
            const int m  = mb + r;
            const float bv = bias[m];
            #pragma unroll
            for (int j = 0; j < 4; ++j) {
                const int n = n0 + wc * 64 + j * 16 + (lane & 15);
                Cp[(size_t)m * NPIX + n] = acc[i][j][r] + bv;
            }
        }
    }
}

// ---------------------------------------------------------------------------
// QK^T split-K partial: part[bh][s][d][e] = sum_{n in split s} q[d,n]*k[e,n]
// ---------------------------------------------------------------------------
__global__ __launch_bounds__(256) void qk_partial_kernel(
    const float* __restrict__ qkv, float* __restrict__ part)
{
    const int s  = blockIdx.x;
    const int bh = blockIdx.y;
    const int b = bh >> 3, h = bh & 7;
    const float* qbase = qkv + ((size_t)b * OC3 + h * HDIM) * NPIX;
    const float* kbase = qkv + ((size_t)b * OC3 + CH + h * HDIM) * NPIX;

    __shared__ f32x4 qs4[64 * 16];
    __shared__ f32x4 ks4[64 * 16];

    const int t  = threadIdx.x;
    const int tx = t & 15, ty = t >> 4;

    float acc[4][4] = {};

    for (int nc = 0; nc < 4; ++nc) {
        const int n0 = s * 256 + nc * 64;
        #pragma unroll
        for (int i = 0; i < 4; ++i) {
            const int lin = t + 256 * i;        // 0..1023
            const int row = lin >> 4;           // 0..63
            const int sl  = lin & 15;           // float4 slot
            qs4[row * 16 + (sl ^ (row & 15))] =
                *(const f32x4*)(qbase + (size_t)row * NPIX + n0 + sl * 4);
            ks4[row * 16 + (sl ^ (row & 15))] =
                *(const f32x4*)(kbase + (size_t)row * NPIX + n0 + sl * 4);
        }
        __syncthreads();

        #pragma unroll
        for (int kk4 = 0; kk4 < 16; ++kk4) {
            f32x4 qf[4], kf[4];
            #pragma unroll
            for (int i = 0; i < 4; ++i)
                qf[i] = qs4[(ty + 16 * i) * 16 + (kk4 ^ ty)];
            #pragma unroll
            for (int j = 0; j < 4; ++j)
                kf[j] = ks4[(tx + 16 * j) * 16 + (kk4 ^ tx)];
            #pragma unroll
            for (int i = 0; i < 4; ++i)
                #pragma unroll
                for (int j = 0; j < 4; ++j) {
                    acc[i][j] = fmaf(qf[i][0], kf[j][0], acc[i][j]);
                    acc[i][j] = fmaf(qf[i][1], kf[j][1], acc[i][j]);
                    acc[i][j] = fmaf(qf[i][2], kf[j][2], acc[i][j]);
                    acc[i][j] = fmaf(qf[i][3], kf[j][3], acc[i][j]);
                }
        }
        __syncthreads();
    }

    float* pb = part + (((size_t)bh * NSPLIT + s) * 64) * 64;
    #pragma unroll
    for (int i = 0; i < 4; ++i)
        #pragma unroll
        for (int j = 0; j < 4; ++j)
            pb[(ty + 16 * i) * 64 + tx + 16 * j] = acc[i][j];
}

// ---------------------------------------------------------------------------
// Reduce partials + row softmax -> attn[bh][d][e] (fp32)
// ---------------------------------------------------------------------------
__global__ __launch_bounds__(256) void qk_reduce_softmax_kernel(
    const float* __restrict__ part, float* __restrict__ attn)
{
    const int bh = blockIdx.x;
    const int t  = threadIdx.x;
    const int r  = t >> 2;
    const int e0 = (t & 3) * 16;

    float v[16];
    #pragma unroll
    for (int i = 0; i < 16; ++i) v[i] = 0.f;

    const float* pb = part + ((size_t)bh * NSPLIT * 64) * 64 + r * 64 + e0;
    for (int s = 0; s < NSPLIT; ++s) {
        const float* ps = pb + (size_t)s * 4096;
        #pragma unroll
        for (int c4 = 0; c4 < 4; ++c4) {
            const float4 p = *(const float4*)(ps + c4 * 4);
            v[c4 * 4 + 0] += p.x; v[c4 * 4 + 1] += p.y;
            v[c4 * 4 + 2] += p.z; v[c4 * 4 + 3] += p.w;
        }
    }

    float m = -1e30f;
    #pragma unroll
    for (int i = 0; i < 16; ++i) m = fmaxf(m, v[i]);
    m = fmaxf(m, __shfl_xor(m, 1));
    m = fmaxf(m, __shfl_xor(m, 2));

    float sum = 0.f;
    #pragma unroll
    for (int i = 0; i < 16; ++i) {
        v[i] = __expf((v[i] - m) * SCALE);
        sum += v[i];
    }
    sum += __shfl_xor(sum, 1);
    sum += __shfl_xor(sum, 2);
    const float inv = 1.f / sum;

    float* arow = attn + ((size_t)bh * 64 + r) * 64 + e0;
    #pragma unroll
    for (int c4 = 0; c4 < 4; ++c4) {
        float4 o;
        o.x = v[c4 * 4 + 0] * inv; o.y = v[c4 * 4 + 1] * inv;
        o.z = v[c4 * 4 + 2] * inv; o.w = v[c4 * 4 + 3] * inv;
        *(float4*)(arow + c4 * 4) = o;
    }
}

// ---------------------------------------------------------------------------
// attn_mean[b][d][e] = mean_h attn[b][h][d][e]
// ---------------------------------------------------------------------------
__global__ __launch_bounds__(256) void attn_mean_kernel(
    const float* __restrict__ attn, float* __restrict__ om)
{
    const int idx = blockIdx.x * 256 + threadIdx.x;
    const int b = idx >> 12, de = idx & 4095;
    float s = 0.f;
    #pragma unroll
    for (int h = 0; h < 8; ++h)
        s += attn[(((size_t)b * 8 + h) << 12) + de];
    om[idx] = s * 0.125f;
}

// ---------------------------------------------------------------------------
// W'[b][o][h*64+e] = sum_d proj_w[o][h*64+d] * attn[b,h,d,e]   (fp32 -> bf16)
// grid (512/64, HEADS, BATCH), 256 thr, 4x4 micro-tile.
// Folds the PV step into the proj GEMM's weights (associativity).
// ---------------------------------------------------------------------------
__global__ __launch_bounds__(256) void wprime_kernel(
    const float* __restrict__ proj_w, const float* __restrict__ attn,
    bf16* __restrict__ wp)
{
    const int o0 = blockIdx.x * 64;
    const int h  = blockIdx.y;
    const int b  = blockIdx.z;

    __shared__ float ws[64][65];   // proj_w[o_local][d]
    __shared__ float as_[64][65];  // attn[d][e]

    const int t = threadIdx.x;
    #pragma unroll
    for (int i = 0; i < 4; ++i) {
        const int lin = t + 256 * i;      // 0..1023
        const int r   = lin >> 4;         // 0..63
        const int c4  = (lin & 15) * 4;
        const float4 wv = *(const float4*)(proj_w + (size_t)(o0 + r) * CH + h * HDIM + c4);
        ws[r][c4 + 0] = wv.x; ws[r][c4 + 1] = wv.y;
        ws[r][c4 + 2] = wv.z; ws[r][c4 + 3] = wv.w;
        const float4 av = *(const float4*)(attn + (((size_t)(b * 8 + h) * 64) + r) * 64 + c4);
        as_[r][c4 + 0] = av.x; as_[r][c4 + 1] = av.y;
        as_[r][c4 + 2] = av.z; as_[r][c4 + 3] = av.w;
    }
    __syncthreads();

    const int tx = t & 15, ty = t >> 4;
    const int to = ty * 4, te = tx * 4;
    float acc[4][4] = {};
    for (int d = 0; d < 64; ++d) {
        float a[4], bb[4];
        #pragma unroll
        for (int i = 0; i < 4; ++i) a[i]  = ws[to + i][d];
        #pragma unroll
        for (int j = 0; j < 4; ++j) bb[j] = as_[d][te + j];
        #pragma unroll
        for (int i = 0; i < 4; ++i)
            #pragma unroll
            for (int j = 0; j < 4; ++j)
                acc[i][j] = fmaf(a[i], bb[j], acc[i][j]);
    }

    bf16* wb = wp + (size_t)b * CH * CH;
    #pragma unroll
    for (int i = 0; i < 4; ++i)
        #pragma unroll
        for (int j = 0; j < 4; ++j)
            wb[(size_t)(o0 + to + i) * CH + h * HDIM + te + j] = (bf16)acc[i][j];
}

// ---------------------------------------------------------------------------
extern "C" void kernel_launch(void* const* d_in, const int* in_sizes, int n_in,
                              void* d_out, int out_size, void* d_ws, size_t ws_size,
                              hipStream_t stream)
{
    (void)in_sizes; (void)n_in; (void)out_size;
    const float* x      = (const float*)d_in[0];
    const float* qkv_w  = (const float*)d_in[1];
    const float* qkv_b  = (const float*)d_in[2];
    const float* proj_w = (const float*)d_in[3];
    const float* proj_b = (const float*)d_in[4];

    float* out       = (float*)d_out;
    float* attn_mean = out + (size_t)BATCH * CH * NPIX;

    const size_t qkv_bytes  = (size_t)BATCH * OC3 * NPIX * 4;          // 192 MiB
    const size_t xt_bytes   = (size_t)BATCH * NPIX * KDEPTH * 2;       //  32 MiB (reused as vt)
    const size_t wq_bytes   = (size_t)OC3 * KDEPTH * 2;                // 1.5 MiB
    const size_t attn_bytes = (size_t)BATCH * HEADS * HDIM * HDIM * 4; //   1 MiB
    const size_t part_bytes = (size_t)BATCH * HEADS * NSPLIT * HDIM * HDIM * 4; // 16 MiB
    const size_t wp_bytes   = (size_t)BATCH * CH * CH * 2;             //   4 MiB
    const size_t need = qkv_bytes + xt_bytes + wq_bytes + attn_bytes + part_bytes + wp_bytes;
    if (ws_size < need) {
        fprintf(stderr, "[kernel_launch] ws_size=%zu < need=%zu — abort\n", ws_size, need);
        fflush(stderr);
        return;
    }

    char* p = (char*)d_ws;
    float* qkv   = (float*)p;             p += qkv_bytes;
    bf16*  xt    = (bf16*)p;              p += xt_bytes;
    bf16*  wq_b  = (bf16*)p;              p += wq_bytes;
    float* attn  = (float*)p;             p += attn_bytes;
    float* part  = (float*)p;             p += part_bytes;
    bf16*  wprime = (bf16*)p;
    bf16*  vt    = xt;   // xt is dead after the QKV GEMM

    // 0) weight convert (QKV only; proj weights are consumed fp32 by wprime)
    convert_bf16_kernel<<<dim3((OC3 * KDEPTH + 255) / 256), 256, 0, stream>>>(
        qkv_w, wq_b, OC3 * KDEPTH);

    // 1) x -> xt (transpose + bf16)
    transpose_convert_kernel<<<dim3(NPIX / 64, KDEPTH / 64, BATCH), 256, 0, stream>>>(
        x, xt, (size_t)CH * NPIX);

    // 2) QKV GEMM (MFMA)
    mfma_gemm_kernel<<<dim3(NPIX / 128, OC3 / 128, BATCH), 256, 0, stream>>>(
        wq_b, xt, qkv_b, qkv, OC3, 0);

    // 3) QK^T split-K + softmax
    qk_partial_kernel<<<dim3(NSPLIT, BATCH * HEADS), 256, 0, stream>>>(qkv, part);
    qk_reduce_softmax_kernel<<<dim3(BATCH * HEADS), 256, 0, stream>>>(part, attn);

    // 4) attn mean over heads (output 1)
    attn_mean_kernel<<<dim3(BATCH * HDIM * HDIM / 256), 256, 0, stream>>>(attn, attn_mean);

    // 5) V region of qkv -> vt (transpose + bf16), into dead xt buffer
    transpose_convert_kernel<<<dim3(NPIX / 64, KDEPTH / 64, BATCH), 256, 0, stream>>>(
        qkv + (size_t)2 * CH * NPIX, vt, (size_t)OC3 * NPIX);

    // 6) W' = proj_w · blockdiag(attn)  (fp32 compute, bf16 out)
    wprime_kernel<<<dim3(CH / 64, HEADS, BATCH), 256, 0, stream>>>(proj_w, attn, wprime);

    // 7) out = W'_b · V_b + proj_b  (MFMA, per-batch A)
    mfma_gemm_kernel<<<dim3(NPIX / 128, CH / 128, BATCH), 256, 0, stream>>>(
        wprime, vt, proj_b, out, CH, (size_t)CH * CH);
}

// Round 7
// 209.364 us; speedup vs baseline: 5.4522x; 1.0303x over previous
//
#include <hip/hip_runtime.h>
#include <cstdio>
#include <cstdint>

// Problem constants
#define BATCH 8
#define CH    512
#define OC3   1536      // 3*CH
#define QKROWS 1024     // Q+K channel rows kept in fp32
#define NPIX  4096      // 64*64
#define HEADS 8
#define HDIM  64
#define KDEPTH 512      // GEMM K
#define SCALE 0.125f    // 64^-0.5
#define NSPLIT 16       // split-K factor for QK^T (256 n per split)

typedef __bf16 bf16;
typedef __bf16 bf16x4 __attribute__((ext_vector_type(4)));
typedef __bf16 bf16x8 __attribute__((ext_vector_type(8)));
typedef float  f32x4  __attribute__((ext_vector_type(4)));

// ---------------------------------------------------------------------------
// fp32 -> bf16 flat convert (weights)
// ---------------------------------------------------------------------------
__global__ __launch_bounds__(256) void convert_bf16_kernel(
    const float* __restrict__ in, bf16* __restrict__ out, int n)
{
    const int i = blockIdx.x * 256 + threadIdx.x;
    if (i < n) out[i] = (bf16)in[i];
}

// ---------------------------------------------------------------------------
// src [b][512][4096] fp32 -> dst [b][4096][512] bf16 (transpose + convert)
// ---------------------------------------------------------------------------
__global__ __launch_bounds__(256) void transpose_convert_kernel(
    const float* __restrict__ src, bf16* __restrict__ dst, size_t src_bstride)
{
    const int b  = blockIdx.z;
    const int n0 = blockIdx.x * 64;
    const int c0 = blockIdx.y * 64;
    __shared__ float tile[64][65];
    const int t = threadIdx.x;
    const float* xp = src + (size_t)b * src_bstride;

    #pragma unroll
    for (int i = 0; i < 4; ++i) {
        const int lin = t + 256 * i;
        const int r   = lin >> 4;
        const int c4  = (lin & 15) * 4;
        const float4 v = *(const float4*)(xp + (size_t)(c0 + r) * 4096 + n0 + c4);
        tile[r][c4 + 0] = v.x; tile[r][c4 + 1] = v.y;
        tile[r][c4 + 2] = v.z; tile[r][c4 + 3] = v.w;
    }
    __syncthreads();

    bf16* op = dst + (size_t)b * 4096 * 512;
    #pragma unroll
    for (int i = 0; i < 2; ++i) {
        const int lin = t + 256 * i;
        const int n   = lin >> 3;
        const int c8  = (lin & 7) * 8;
        bf16x8 v;
        #pragma unroll
        for (int jj = 0; jj < 8; ++jj) v[jj] = (bf16)tile[c8 + jj][n];
        *(bf16x8*)(op + (size_t)(n0 + n) * 512 + c0 + c8) = v;
    }
}

// ---------------------------------------------------------------------------
// MFMA GEMM: acc[b][m][n] = sum_k A[b][m][k] * Bt[b][n][k] + bias[m]
//  - m0 <  v_base: write fp32 C[b][m][n]       (C rows/batch = c_rows)
//  - m0 >= v_base: write bf16 vt[b][n][m-v_base] via LDS transpose (fused
//    V transpose: kills the fp32 V write + re-read)
// 128x128 tile, BK=32, 4 waves (2x2), global_load_lds width=16 staging.
// ---------------------------------------------------------------------------
__global__ __launch_bounds__(256) void mfma_gemm_kernel(
    const bf16* __restrict__ A, const bf16* __restrict__ Bt,
    const float* __restrict__ bias, float* __restrict__ C,
    bf16* __restrict__ vt, int v_base, int c_rows, size_t a_bstride)
{
    const int b  = blockIdx.z;
    const int m0 = blockIdx.y * 128;
    const int n0 = blockIdx.x * 128;
    const bf16* Ap = A  + (size_t)b * a_bstride;
    const bf16* Bp = Bt + (size_t)b * NPIX * KDEPTH;

    // As/Bs (2x4096) and the 64x132 transpose buffer alias the same LDS.
    __shared__ bf16 smem[8448];
    bf16* As = smem;
    bf16* Bs = smem + 4096;

    const int t    = threadIdx.x;
    const int lane = t & 63;
    const int wave = t >> 6;
    const int wr   = wave >> 1, wc = wave & 1;

    f32x4 acc[4][4];
    const f32x4 zf = {0.f, 0.f, 0.f, 0.f};
    #pragma unroll
    for (int i = 0; i < 4; ++i)
        #pragma unroll
        for (int j = 0; j < 4; ++j) acc[i][j] = zf;

    for (int k0 = 0; k0 < KDEPTH; k0 += 32) {
        #pragma unroll
        for (int i = 0; i < 2; ++i) {
            const int c   = t + 256 * i;    // 0..511 16B-chunks
            const int row = c >> 2;         // 0..127
            const int kb  = (c & 3) * 8;    // k element offset
            __builtin_amdgcn_global_load_lds(
                (const __attribute__((address_space(1))) void*)(Ap + (size_t)(m0 + row) * KDEPTH + k0 + kb),
                (__attribute__((address_space(3))) void*)(As + c * 8), 16, 0, 0);
            __builtin_amdgcn_global_load_lds(
                (const __attribute__((address_space(1))) void*)(Bp + (size_t)(n0 + row) * KDEPTH + k0 + kb),
                (__attribute__((address_space(3))) void*)(Bs + c * 8), 16, 0, 0);
        }
        __syncthreads();

        bf16x8 af[4], bfv[4];
        #pragma unroll
        for (int i = 0; i < 4; ++i) {
            const int ar = wr * 64 + i * 16 + (lane & 15);
            af[i]  = *(const bf16x8*)(As + ar * 32 + (lane >> 4) * 8);
            const int br = wc * 64 + i * 16 + (lane & 15);
            bfv[i] = *(const bf16x8*)(Bs + br * 32 + (lane >> 4) * 8);
        }
        #pragma unroll
        for (int i = 0; i < 4; ++i)
            #pragma unroll
            for (int j = 0; j < 4; ++j)
                acc[i][j] = __builtin_amdgcn_mfma_f32_16x16x32_bf16(
                    af[i], bfv[j], acc[i][j], 0, 0, 0);
        __syncthreads();
    }

    if (m0 < v_base) {
        // fp32 epilogue (Q/K rows, or the whole proj GEMM)
        float* Cp = C + (size_t)b * c_rows * NPIX;
        #pragma unroll
        for (int i = 0; i < 4; ++i) {
            const int mb = m0 + wr * 64 + i * 16 + (lane >> 4) * 4;
            #pragma unroll
            for (int r = 0; r < 4; ++r) {
                const int m  = mb + r;
                const float bv = bias[m];
                #pragma unroll
                for (int j = 0; j < 4; ++j) {
                    const int n = n0 + wc * 64 + j * 16 + (lane & 15);
                    Cp[(size_t)m * NPIX + n] = acc[i][j][r] + bv;
                }
            }
        }
    } else {
        // fused V epilogue: bf16 + transpose -> vt[b][n][c], c = m - v_base
        const int cbase = m0 - v_base;
        bf16* vb = vt + (size_t)b * NPIX * KDEPTH;
        bf16* tb = smem;   // 64 x 132 bf16 (aliases As/Bs, dead now)
        #pragma unroll
        for (int p = 0; p < 2; ++p) {
            if (wc == p) {
                #pragma unroll
                for (int i = 0; i < 4; ++i) {
                    const int ml = wr * 64 + i * 16 + (lane >> 4) * 4;
                    #pragma unroll
                    for (int j = 0; j < 4; ++j) {
                        const int ns = j * 16 + (lane & 15);
                        bf16x4 pk;
                        #pragma unroll
                        for (int r = 0; r < 4; ++r)
                            pk[r] = (bf16)(acc[i][j][r] + bias[m0 + ml + r]);
                        *(bf16x4*)(tb + ns * 132 + ml) = pk;
                    }
                }
            }
            __syncthreads();
            #pragma unroll
            for (int ii = 0; ii < 4; ++ii) {
                const int lin = t + 256 * ii;   // 0..1023
                const int row = lin >> 4;       // n_sub 0..63
                const int seg = lin & 15;       // 8-elem segment
                const int4 v = *(const int4*)(tb + row * 132 + seg * 8);
                *(int4*)(vb + (size_t)(n0 + p * 64 + row) * KDEPTH + cbase + seg * 8) = v;
            }
            __syncthreads();
        }
    }
}

// ---------------------------------------------------------------------------
// QK^T split-K partial: part[bh][s][d][e] = sum_{n in split s} q[d,n]*k[e,n]
// qk: [b][1024][4096] fp32 (Q rows 0..511, K rows 512..1023)
// ---------------------------------------------------------------------------
__global__ __launch_bounds__(256) void qk_partial_kernel(
    const float* __restrict__ qk, float* __restrict__ part)
{
    const int s  = blockIdx.x;
    const int bh = blockIdx.y;
    const int b = bh >> 3, h = bh & 7;
    const float* qbase = qk + ((size_t)b * QKROWS + h * HDIM) * NPIX;
    const float* kbase = qk + ((size_t)b * QKROWS + CH + h * HDIM) * NPIX;

    __shared__ f32x4 qs4[64 * 16];
    __shared__ f32x4 ks4[64 * 16];

    const int t  = threadIdx.x;
    const int tx = t & 15, ty = t >> 4;

    float acc[4][4] = {};

    for (int nc = 0; nc < 4; ++nc) {
        const int n0 = s * 256 + nc * 64;
        #pragma unroll
        for (int i = 0; i < 4; ++i) {
            const int lin = t + 256 * i;        // 0..1023
            const int row = lin >> 4;           // 0..63
            const int sl  = lin & 15;           // float4 slot
            qs4[row * 16 + (sl ^ (row & 15))] =
                *(const f32x4*)(qbase + (size_t)row * NPIX + n0 + sl * 4);
            ks4[row * 16 + (sl ^ (row & 15))] =
                *(const f32x4*)(kbase + (size_t)row * NPIX + n0 + sl * 4);
        }
        __syncthreads();

        #pragma unroll
        for (int kk4 = 0; kk4 < 16; ++kk4) {
            f32x4 qf[4], kf[4];
            #pragma unroll
            for (int i = 0; i < 4; ++i)
                qf[i] = qs4[(ty + 16 * i) * 16 + (kk4 ^ ty)];
            #pragma unroll
            for (int j = 0; j < 4; ++j)
                kf[j] = ks4[(tx + 16 * j) * 16 + (kk4 ^ tx)];
            #pragma unroll
            for (int i = 0; i < 4; ++i)
                #pragma unroll
                for (int j = 0; j < 4; ++j) {
                    acc[i][j] = fmaf(qf[i][0], kf[j][0], acc[i][j]);
                    acc[i][j] = fmaf(qf[i][1], kf[j][1], acc[i][j]);
                    acc[i][j] = fmaf(qf[i][2], kf[j][2], acc[i][j]);
                    acc[i][j] = fmaf(qf[i][3], kf[j][3], acc[i][j]);
                }
        }
        __syncthreads();
    }

    float* pb = part + (((size_t)bh * NSPLIT + s) * 64) * 64;
    #pragma unroll
    for (int i = 0; i < 4; ++i)
        #pragma unroll
        for (int j = 0; j < 4; ++j)
            pb[(ty + 16 * i) * 64 + tx + 16 * j] = acc[i][j];
}

// ---------------------------------------------------------------------------
// Reduce partials + row softmax -> attn[bh][d][e] (fp32)
// ---------------------------------------------------------------------------
__global__ __launch_bounds__(256) void qk_reduce_softmax_kernel(
    const float* __restrict__ part, float* __restrict__ attn)
{
    const int bh = blockIdx.x;
    const int t  = threadIdx.x;
    const int r  = t >> 2;
    const int e0 = (t & 3) * 16;

    float v[16];
    #pragma unroll
    for (int i = 0; i < 16; ++i) v[i] = 0.f;

    const float* pb = part + ((size_t)bh * NSPLIT * 64) * 64 + r * 64 + e0;
    for (int s = 0; s < NSPLIT; ++s) {
        const float* ps = pb + (size_t)s * 4096;
        #pragma unroll
        for (int c4 = 0; c4 < 4; ++c4) {
            const float4 p = *(const float4*)(ps + c4 * 4);
            v[c4 * 4 + 0] += p.x; v[c4 * 4 + 1] += p.y;
            v[c4 * 4 + 2] += p.z; v[c4 * 4 + 3] += p.w;
        }
    }

    float m = -1e30f;
    #pragma unroll
    for (int i = 0; i < 16; ++i) m = fmaxf(m, v[i]);
    m = fmaxf(m, __shfl_xor(m, 1));
    m = fmaxf(m, __shfl_xor(m, 2));

    float sum = 0.f;
    #pragma unroll
    for (int i = 0; i < 16; ++i) {
        v[i] = __expf((v[i] - m) * SCALE);
        sum += v[i];
    }
    sum += __shfl_xor(sum, 1);
    sum += __shfl_xor(sum, 2);
    const float inv = 1.f / sum;

    float* arow = attn + ((size_t)bh * 64 + r) * 64 + e0;
    #pragma unroll
    for (int c4 = 0; c4 < 4; ++c4) {
        float4 o;
        o.x = v[c4 * 4 + 0] * inv; o.y = v[c4 * 4 + 1] * inv;
        o.z = v[c4 * 4 + 2] * inv; o.w = v[c4 * 4 + 3] * inv;
        *(float4*)(arow + c4 * 4) = o;
    }
}

// ---------------------------------------------------------------------------
// attn_mean[b][d][e] = mean_h attn[b][h][d][e]
// ---------------------------------------------------------------------------
__global__ __launch_bounds__(256) void attn_mean_kernel(
    const float* __restrict__ attn, float* __restrict__ om)
{
    const int idx = blockIdx.x * 256 + threadIdx.x;
    const int b = idx >> 12, de = idx & 4095;
    float s = 0.f;
    #pragma unroll
    for (int h = 0; h < 8; ++h)
        s += attn[(((size_t)b * 8 + h) << 12) + de];
    om[idx] = s * 0.125f;
}

// ---------------------------------------------------------------------------
// W'[b][o][h*64+e] = sum_d proj_w[o][h*64+d] * attn[b,h,d,e]   (fp32 -> bf16)
// ---------------------------------------------------------------------------
__global__ __launch_bounds__(256) void wprime_kernel(
    const float* __restrict__ proj_w, const float* __restrict__ attn,
    bf16* __restrict__ wp)
{
    const int o0 = blockIdx.x * 64;
    const int h  = blockIdx.y;
    const int b  = blockIdx.z;

    __shared__ float ws[64][65];   // proj_w[o_local][d]
    __shared__ float as_[64][65];  // attn[d][e]

    const int t = threadIdx.x;
    #pragma unroll
    for (int i = 0; i < 4; ++i) {
        const int lin = t + 256 * i;      // 0..1023
        const int r   = lin >> 4;         // 0..63
        const int c4  = (lin & 15) * 4;
        const float4 wv = *(const float4*)(proj_w + (size_t)(o0 + r) * CH + h * HDIM + c4);
        ws[r][c4 + 0] = wv.x; ws[r][c4 + 1] = wv.y;
        ws[r][c4 + 2] = wv.z; ws[r][c4 + 3] = wv.w;
        const float4 av = *(const float4*)(attn + (((size_t)(b * 8 + h) * 64) + r) * 64 + c4);
        as_[r][c4 + 0] = av.x; as_[r][c4 + 1] = av.y;
        as_[r][c4 + 2] = av.z; as_[r][c4 + 3] = av.w;
    }
    __syncthreads();

    const int tx = t & 15, ty = t >> 4;
    const int to = ty * 4, te = tx * 4;
    float acc[4][4] = {};
    for (int d = 0; d < 64; ++d) {
        float a[4], bb[4];
        #pragma unroll
        for (int i = 0; i < 4; ++i) a[i]  = ws[to + i][d];
        #pragma unroll
        for (int j = 0; j < 4; ++j) bb[j] = as_[d][te + j];
        #pragma unroll
        for (int i = 0; i < 4; ++i)
            #pragma unroll
            for (int j = 0; j < 4; ++j)
                acc[i][j] = fmaf(a[i], bb[j], acc[i][j]);
    }

    bf16* wb = wp + (size_t)b * CH * CH;
    #pragma unroll
    for (int i = 0; i < 4; ++i)
        #pragma unroll
        for (int j = 0; j < 4; ++j)
            wb[(size_t)(o0 + to + i) * CH + h * HDIM + te + j] = (bf16)acc[i][j];
}

// ---------------------------------------------------------------------------
extern "C" void kernel_launch(void* const* d_in, const int* in_sizes, int n_in,
                              void* d_out, int out_size, void* d_ws, size_t ws_size,
                              hipStream_t stream)
{
    (void)in_sizes; (void)n_in; (void)out_size;
    const float* x      = (const float*)d_in[0];
    const float* qkv_w  = (const float*)d_in[1];
    const float* qkv_b  = (const float*)d_in[2];
    const float* proj_w = (const float*)d_in[3];
    const float* proj_b = (const float*)d_in[4];

    float* out       = (float*)d_out;
    float* attn_mean = out + (size_t)BATCH * CH * NPIX;

    const size_t qk_bytes   = (size_t)BATCH * QKROWS * NPIX * 4;        // 128 MiB
    const size_t xt_bytes   = (size_t)BATCH * NPIX * KDEPTH * 2;        //  32 MiB
    const size_t vt_bytes   = (size_t)BATCH * NPIX * KDEPTH * 2;        //  32 MiB
    const size_t wq_bytes   = (size_t)OC3 * KDEPTH * 2;                 // 1.5 MiB
    const size_t attn_bytes = (size_t)BATCH * HEADS * HDIM * HDIM * 4;  //   1 MiB
    const size_t part_bytes = (size_t)BATCH * HEADS * NSPLIT * HDIM * HDIM * 4; // 16 MiB
    const size_t wp_bytes   = (size_t)BATCH * CH * CH * 2;              //   4 MiB
    const size_t need = qk_bytes + xt_bytes + vt_bytes + wq_bytes + attn_bytes + part_bytes + wp_bytes;
    if (ws_size < need) {
        fprintf(stderr, "[kernel_launch] ws_size=%zu < need=%zu — abort\n", ws_size, need);
        fflush(stderr);
        return;
    }

    char* p = (char*)d_ws;
    float* qk     = (float*)p;            p += qk_bytes;
    bf16*  xt     = (bf16*)p;             p += xt_bytes;
    bf16*  vt     = (bf16*)p;             p += vt_bytes;
    bf16*  wq_b   = (bf16*)p;             p += wq_bytes;
    float* attn   = (float*)p;            p += attn_bytes;
    float* part   = (float*)p;            p += part_bytes;
    bf16*  wprime = (bf16*)p;

    // 0) QKV weight convert
    convert_bf16_kernel<<<dim3((OC3 * KDEPTH + 255) / 256), 256, 0, stream>>>(
        qkv_w, wq_b, OC3 * KDEPTH);

    // 1) x -> xt (transpose + bf16)
    transpose_convert_kernel<<<dim3(NPIX / 64, KDEPTH / 64, BATCH), 256, 0, stream>>>(
        x, xt, (size_t)CH * NPIX);

    // 2) QKV GEMM: Q,K rows -> fp32 qk; V rows -> bf16 vt (fused transpose)
    mfma_gemm_kernel<<<dim3(NPIX / 128, OC3 / 128, BATCH), 256, 0, stream>>>(
        wq_b, xt, qkv_b, qk, vt, QKROWS, QKROWS, 0);

    // 3) QK^T split-K + softmax
    qk_partial_kernel<<<dim3(NSPLIT, BATCH * HEADS), 256, 0, stream>>>(qk, part);
    qk_reduce_softmax_kernel<<<dim3(BATCH * HEADS), 256, 0, stream>>>(part, attn);

    // 4) attn mean over heads (output 1)
    attn_mean_kernel<<<dim3(BATCH * HDIM * HDIM / 256), 256, 0, stream>>>(attn, attn_mean);

    // 5) W' = proj_w · blockdiag(attn)
    wprime_kernel<<<dim3(CH / 64, HEADS, BATCH), 256, 0, stream>>>(proj_w, attn, wprime);

    // 6) out = W'_b · V_b + proj_b  (fp32 epilogue only: v_base > M)
    mfma_gemm_kernel<<<dim3(NPIX / 128, CH / 128, BATCH), 256, 0, stream>>>(
        wprime, vt, proj_b, out, nullptr, 1 << 30, CH, (size_t)CH * CH);
}

// Round 8
// 190.271 us; speedup vs baseline: 5.9994x; 1.1003x over previous
//
#include <hip/hip_runtime.h>
#include <cstdio>
#include <cstdint>

// Problem constants
#define BATCH 8
#define CH    512
#define OC3   1536      // 3*CH
#define QKROWS 1024     // Q+K channel rows (bf16)
#define NPIX  4096      // 64*64
#define HEADS 8
#define HDIM  64
#define KDEPTH 512      // GEMM K
#define SCALE 0.125f    // 64^-0.5
#define NSPLIT 16       // split-K factor for QK^T (256 n per split)

typedef __bf16 bf16;
typedef __bf16 bf16x4 __attribute__((ext_vector_type(4)));
typedef __bf16 bf16x8 __attribute__((ext_vector_type(8)));
typedef float  f32x4  __attribute__((ext_vector_type(4)));

// ---------------------------------------------------------------------------
// fp32 -> bf16 flat convert (weights)
// ---------------------------------------------------------------------------
__global__ __launch_bounds__(256) void convert_bf16_kernel(
    const float* __restrict__ in, bf16* __restrict__ out, int n)
{
    const int i = blockIdx.x * 256 + threadIdx.x;
    if (i < n) out[i] = (bf16)in[i];
}

// ---------------------------------------------------------------------------
// src [b][512][4096] fp32 -> dst [b][4096][512] bf16 (transpose + convert)
// ---------------------------------------------------------------------------
__global__ __launch_bounds__(256) void transpose_convert_kernel(
    const float* __restrict__ src, bf16* __restrict__ dst, size_t src_bstride)
{
    const int b  = blockIdx.z;
    const int n0 = blockIdx.x * 64;
    const int c0 = blockIdx.y * 64;
    __shared__ float tile[64][65];
    const int t = threadIdx.x;
    const float* xp = src + (size_t)b * src_bstride;

    #pragma unroll
    for (int i = 0; i < 4; ++i) {
        const int lin = t + 256 * i;
        const int r   = lin >> 4;
        const int c4  = (lin & 15) * 4;
        const float4 v = *(const float4*)(xp + (size_t)(c0 + r) * 4096 + n0 + c4);
        tile[r][c4 + 0] = v.x; tile[r][c4 + 1] = v.y;
        tile[r][c4 + 2] = v.z; tile[r][c4 + 3] = v.w;
    }
    __syncthreads();

    bf16* op = dst + (size_t)b * 4096 * 512;
    #pragma unroll
    for (int i = 0; i < 2; ++i) {
        const int lin = t + 256 * i;
        const int n   = lin >> 3;
        const int c8  = (lin & 7) * 8;
        bf16x8 v;
        #pragma unroll
        for (int jj = 0; jj < 8; ++jj) v[jj] = (bf16)tile[c8 + jj][n];
        *(bf16x8*)(op + (size_t)(n0 + n) * 512 + c0 + c8) = v;
    }
}

// ---------------------------------------------------------------------------
// MFMA GEMM: acc[b][m][n] = sum_k A[b][m][k] * Bt[b][n][k] + bias[m]
// Epilogues:
//  - m0 >= v_base           : bf16 vt[b][n][m-v_base] via LDS transpose
//  - m0 <  v_base && qkb    : bf16 qkb[b][m][n] (Q/K rows, c-major)
//  - else                   : fp32 C[b][m][n]
// 128x128 tile, BK=32, 4 waves (2x2), global_load_lds width=16 staging.
// ---------------------------------------------------------------------------
__global__ __launch_bounds__(256) void mfma_gemm_kernel(
    const bf16* __restrict__ A, const bf16* __restrict__ Bt,
    const float* __restrict__ bias, float* __restrict__ C,
    bf16* __restrict__ qkb, bf16* __restrict__ vt,
    int v_base, int c_rows, size_t a_bstride)
{
    const int b  = blockIdx.z;
    const int m0 = blockIdx.y * 128;
    const int n0 = blockIdx.x * 128;
    const bf16* Ap = A  + (size_t)b * a_bstride;
    const bf16* Bp = Bt + (size_t)b * NPIX * KDEPTH;

    // As/Bs (2x4096) and the 64x132 transpose buffer alias the same LDS.
    __shared__ bf16 smem[8448];
    bf16* As = smem;
    bf16* Bs = smem + 4096;

    const int t    = threadIdx.x;
    const int lane = t & 63;
    const int wave = t >> 6;
    const int wr   = wave >> 1, wc = wave & 1;

    f32x4 acc[4][4];
    const f32x4 zf = {0.f, 0.f, 0.f, 0.f};
    #pragma unroll
    for (int i = 0; i < 4; ++i)
        #pragma unroll
        for (int j = 0; j < 4; ++j) acc[i][j] = zf;

    for (int k0 = 0; k0 < KDEPTH; k0 += 32) {
        #pragma unroll
        for (int i = 0; i < 2; ++i) {
            const int c   = t + 256 * i;    // 0..511 16B-chunks
            const int row = c >> 2;         // 0..127
            const int kb  = (c & 3) * 8;    // k element offset
            __builtin_amdgcn_global_load_lds(
                (const __attribute__((address_space(1))) void*)(Ap + (size_t)(m0 + row) * KDEPTH + k0 + kb),
                (__attribute__((address_space(3))) void*)(As + c * 8), 16, 0, 0);
            __builtin_amdgcn_global_load_lds(
                (const __attribute__((address_space(1))) void*)(Bp + (size_t)(n0 + row) * KDEPTH + k0 + kb),
                (__attribute__((address_space(3))) void*)(Bs + c * 8), 16, 0, 0);
        }
        __syncthreads();

        bf16x8 af[4], bfv[4];
        #pragma unroll
        for (int i = 0; i < 4; ++i) {
            const int ar = wr * 64 + i * 16 + (lane & 15);
            af[i]  = *(const bf16x8*)(As + ar * 32 + (lane >> 4) * 8);
            const int br = wc * 64 + i * 16 + (lane & 15);
            bfv[i] = *(const bf16x8*)(Bs + br * 32 + (lane >> 4) * 8);
        }
        #pragma unroll
        for (int i = 0; i < 4; ++i)
            #pragma unroll
            for (int j = 0; j < 4; ++j)
                acc[i][j] = __builtin_amdgcn_mfma_f32_16x16x32_bf16(
                    af[i], bfv[j], acc[i][j], 0, 0, 0);
        __syncthreads();
    }

    if (m0 >= v_base) {
        // fused V epilogue: bf16 + transpose -> vt[b][n][c], c = m - v_base
        const int cbase = m0 - v_base;
        bf16* vb = vt + (size_t)b * NPIX * KDEPTH;
        bf16* tb = smem;   // 64 x 132 bf16 (aliases As/Bs, dead now)
        #pragma unroll
        for (int p = 0; p < 2; ++p) {
            if (wc == p) {
                #pragma unroll
                for (int i = 0; i < 4; ++i) {
                    const int ml = wr * 64 + i * 16 + (lane >> 4) * 4;
                    #pragma unroll
                    for (int j = 0; j < 4; ++j) {
                        const int ns = j * 16 + (lane & 15);
                        bf16x4 pk;
                        #pragma unroll
                        for (int r = 0; r < 4; ++r)
                            pk[r] = (bf16)(acc[i][j][r] + bias[m0 + ml + r]);
                        *(bf16x4*)(tb + ns * 132 + ml) = pk;
                    }
                }
            }
            __syncthreads();
            #pragma unroll
            for (int ii = 0; ii < 4; ++ii) {
                const int lin = t + 256 * ii;   // 0..1023
                const int row = lin >> 4;       // n_sub 0..63
                const int seg = lin & 15;       // 8-elem segment
                const int4 v = *(const int4*)(tb + row * 132 + seg * 8);
                *(int4*)(vb + (size_t)(n0 + p * 64 + row) * KDEPTH + cbase + seg * 8) = v;
            }
            __syncthreads();
        }
    } else if (qkb) {
        // bf16 Q/K epilogue (c-major, same layout as fp32 was)
        bf16* Qp = qkb + (size_t)b * c_rows * NPIX;
        #pragma unroll
        for (int i = 0; i < 4; ++i) {
            const int mb = m0 + wr * 64 + i * 16 + (lane >> 4) * 4;
            #pragma unroll
            for (int r = 0; r < 4; ++r) {
                const int m  = mb + r;
                const float bv = bias[m];
                #pragma unroll
                for (int j = 0; j < 4; ++j) {
                    const int n = n0 + wc * 64 + j * 16 + (lane & 15);
                    Qp[(size_t)m * NPIX + n] = (bf16)(acc[i][j][r] + bv);
                }
            }
        }
    } else {
        // fp32 epilogue (proj GEMM -> out)
        float* Cp = C + (size_t)b * c_rows * NPIX;
        #pragma unroll
        for (int i = 0; i < 4; ++i) {
            const int mb = m0 + wr * 64 + i * 16 + (lane >> 4) * 4;
            #pragma unroll
            for (int r = 0; r < 4; ++r) {
                const int m  = mb + r;
                const float bv = bias[m];
                #pragma unroll
                for (int j = 0; j < 4; ++j) {
                    const int n = n0 + wc * 64 + j * 16 + (lane & 15);
                    Cp[(size_t)m * NPIX + n] = acc[i][j][r] + bv;
                }
            }
        }
    }
}

// ---------------------------------------------------------------------------
// QK^T split-K partial: part[bh][s][d][e] = sum_{n in split s} q[d,n]*k[e,n]
// qk: [b][1024][4096] bf16 (Q rows 0..511, K rows 512..1023). fp32 accum.
// LDS slot s of row r holds n-group s (4 floats), stored at slot s^(r&15).
// ---------------------------------------------------------------------------
__global__ __launch_bounds__(256) void qk_partial_kernel(
    const bf16* __restrict__ qk, float* __restrict__ part)
{
    const int s  = blockIdx.x;
    const int bh = blockIdx.y;
    const int b = bh >> 3, h = bh & 7;
    const bf16* qbase = qk + ((size_t)b * QKROWS + h * HDIM) * NPIX;
    const bf16* kbase = qk + ((size_t)b * QKROWS + CH + h * HDIM) * NPIX;

    __shared__ f32x4 qs4[64 * 16];
    __shared__ f32x4 ks4[64 * 16];

    const int t  = threadIdx.x;
    const int tx = t & 15, ty = t >> 4;

    float acc[4][4] = {};

    for (int nc = 0; nc < 4; ++nc) {
        const int n0 = s * 256 + nc * 64;
        #pragma unroll
        for (int i = 0; i < 2; ++i) {
            const int lin = t + 256 * i;        // 0..511
            const int row = lin >> 3;           // 0..63
            const int s8  = lin & 7;            // 8-elem group
            const bf16x8 qv = *(const bf16x8*)(qbase + (size_t)row * NPIX + n0 + s8 * 8);
            const bf16x8 kv = *(const bf16x8*)(kbase + (size_t)row * NPIX + n0 + s8 * 8);
            f32x4 qlo = {(float)qv[0], (float)qv[1], (float)qv[2], (float)qv[3]};
            f32x4 qhi = {(float)qv[4], (float)qv[5], (float)qv[6], (float)qv[7]};
            f32x4 klo = {(float)kv[0], (float)kv[1], (float)kv[2], (float)kv[3]};
            f32x4 khi = {(float)kv[4], (float)kv[5], (float)kv[6], (float)kv[7]};
            const int m = row & 15;
            qs4[row * 16 + ((2 * s8) ^ m)]     = qlo;
            qs4[row * 16 + ((2 * s8 + 1) ^ m)] = qhi;
            ks4[row * 16 + ((2 * s8) ^ m)]     = klo;
            ks4[row * 16 + ((2 * s8 + 1) ^ m)] = khi;
        }
        __syncthreads();

        #pragma unroll
        for (int kk4 = 0; kk4 < 16; ++kk4) {
            f32x4 qf[4], kf[4];
            #pragma unroll
            for (int i = 0; i < 4; ++i)
                qf[i] = qs4[(ty + 16 * i) * 16 + (kk4 ^ ty)];
            #pragma unroll
            for (int j = 0; j < 4; ++j)
                kf[j] = ks4[(tx + 16 * j) * 16 + (kk4 ^ tx)];
            #pragma unroll
            for (int i = 0; i < 4; ++i)
                #pragma unroll
                for (int j = 0; j < 4; ++j) {
                    acc[i][j] = fmaf(qf[i][0], kf[j][0], acc[i][j]);
                    acc[i][j] = fmaf(qf[i][1], kf[j][1], acc[i][j]);
                    acc[i][j] = fmaf(qf[i][2], kf[j][2], acc[i][j]);
                    acc[i][j] = fmaf(qf[i][3], kf[j][3], acc[i][j]);
                }
        }
        __syncthreads();
    }

    float* pb = part + (((size_t)bh * NSPLIT + s) * 64) * 64;
    #pragma unroll
    for (int i = 0; i < 4; ++i)
        #pragma unroll
        for (int j = 0; j < 4; ++j)
            pb[(ty + 16 * i) * 64 + tx + 16 * j] = acc[i][j];
}

// ---------------------------------------------------------------------------
// Reduce partials + row softmax -> attn[bh][d][e] (fp32)
// ---------------------------------------------------------------------------
__global__ __launch_bounds__(256) void qk_reduce_softmax_kernel(
    const float* __restrict__ part, float* __restrict__ attn)
{
    const int bh = blockIdx.x;
    const int t  = threadIdx.x;
    const int r  = t >> 2;
    const int e0 = (t & 3) * 16;

    float v[16];
    #pragma unroll
    for (int i = 0; i < 16; ++i) v[i] = 0.f;

    const float* pb = part + ((size_t)bh * NSPLIT * 64) * 64 + r * 64 + e0;
    for (int s = 0; s < NSPLIT; ++s) {
        const float* ps = pb + (size_t)s * 4096;
        #pragma unroll
        for (int c4 = 0; c4 < 4; ++c4) {
            const float4 p = *(const float4*)(ps + c4 * 4);
            v[c4 * 4 + 0] += p.x; v[c4 * 4 + 1] += p.y;
            v[c4 * 4 + 2] += p.z; v[c4 * 4 + 3] += p.w;
        }
    }

    float m = -1e30f;
    #pragma unroll
    for (int i = 0; i < 16; ++i) m = fmaxf(m, v[i]);
    m = fmaxf(m, __shfl_xor(m, 1));
    m = fmaxf(m, __shfl_xor(m, 2));

    float sum = 0.f;
    #pragma unroll
    for (int i = 0; i < 16; ++i) {
        v[i] = __expf((v[i] - m) * SCALE);
        sum += v[i];
    }
    sum += __shfl_xor(sum, 1);
    sum += __shfl_xor(sum, 2);
    const float inv = 1.f / sum;

    float* arow = attn + ((size_t)bh * 64 + r) * 64 + e0;
    #pragma unroll
    for (int c4 = 0; c4 < 4; ++c4) {
        float4 o;
        o.x = v[c4 * 4 + 0] * inv; o.y = v[c4 * 4 + 1] * inv;
        o.z = v[c4 * 4 + 2] * inv; o.w = v[c4 * 4 + 3] * inv;
        *(float4*)(arow + c4 * 4) = o;
    }
}

// ---------------------------------------------------------------------------
// attn_mean[b][d][e] = mean_h attn[b][h][d][e]
// ---------------------------------------------------------------------------
__global__ __launch_bounds__(256) void attn_mean_kernel(
    const float* __restrict__ attn, float* __restrict__ om)
{
    const int idx = blockIdx.x * 256 + threadIdx.x;
    const int b = idx >> 12, de = idx & 4095;
    float s = 0.f;
    #pragma unroll
    for (int h = 0; h < 8; ++h)
        s += attn[(((size_t)b * 8 + h) << 12) + de];
    om[idx] = s * 0.125f;
}

// ---------------------------------------------------------------------------
// W'[b][o][h*64+e] = sum_d proj_w[o][h*64+d] * attn[b,h,d,e]   (fp32 -> bf16)
// ---------------------------------------------------------------------------
__global__ __launch_bounds__(256) void wprime_kernel(
    const float* __restrict__ proj_w, const float* __restrict__ attn,
    bf16* __restrict__ wp)
{
    const int o0 = blockIdx.x * 64;
    const int h  = blockIdx.y;
    const int b  = blockIdx.z;

    __shared__ float ws[64][65];   // proj_w[o_local][d]
    __shared__ float as_[64][65];  // attn[d][e]

    const int t = threadIdx.x;
    #pragma unroll
    for (int i = 0; i < 4; ++i) {
        const int lin = t + 256 * i;      // 0..1023
        const int r   = lin >> 4;         // 0..63
        const int c4  = (lin & 15) * 4;
        const float4 wv = *(const float4*)(proj_w + (size_t)(o0 + r) * CH + h * HDIM + c4);
        ws[r][c4 + 0] = wv.x; ws[r][c4 + 1] = wv.y;
        ws[r][c4 + 2] = wv.z; ws[r][c4 + 3] = wv.w;
        const float4 av = *(const float4*)(attn + (((size_t)(b * 8 + h) * 64) + r) * 64 + c4);
        as_[r][c4 + 0] = av.x; as_[r][c4 + 1] = av.y;
        as_[r][c4 + 2] = av.z; as_[r][c4 + 3] = av.w;
    }
    __syncthreads();

    const int tx = t & 15, ty = t >> 4;
    const int to = ty * 4, te = tx * 4;
    float acc[4][4] = {};
    for (int d = 0; d < 64; ++d) {
        float a[4], bb[4];
        #pragma unroll
        for (int i = 0; i < 4; ++i) a[i]  = ws[to + i][d];
        #pragma unroll
        for (int j = 0; j < 4; ++j) bb[j] = as_[d][te + j];
        #pragma unroll
        for (int i = 0; i < 4; ++i)
            #pragma unroll
            for (int j = 0; j < 4; ++j)
                acc[i][j] = fmaf(a[i], bb[j], acc[i][j]);
    }

    bf16* wb = wp + (size_t)b * CH * CH;
    #pragma unroll
    for (int i = 0; i < 4; ++i)
        #pragma unroll
        for (int j = 0; j < 4; ++j)
            wb[(size_t)(o0 + to + i) * CH + h * HDIM + te + j] = (bf16)acc[i][j];
}

// ---------------------------------------------------------------------------
extern "C" void kernel_launch(void* const* d_in, const int* in_sizes, int n_in,
                              void* d_out, int out_size, void* d_ws, size_t ws_size,
                              hipStream_t stream)
{
    (void)in_sizes; (void)n_in; (void)out_size;
    const float* x      = (const float*)d_in[0];
    const float* qkv_w  = (const float*)d_in[1];
    const float* qkv_b  = (const float*)d_in[2];
    const float* proj_w = (const float*)d_in[3];
    const float* proj_b = (const float*)d_in[4];

    float* out       = (float*)d_out;
    float* attn_mean = out + (size_t)BATCH * CH * NPIX;

    const size_t qk_bytes   = (size_t)BATCH * QKROWS * NPIX * 2;        //  64 MiB (bf16)
    const size_t xt_bytes   = (size_t)BATCH * NPIX * KDEPTH * 2;        //  32 MiB
    const size_t vt_bytes   = (size_t)BATCH * NPIX * KDEPTH * 2;        //  32 MiB
    const size_t wq_bytes   = (size_t)OC3 * KDEPTH * 2;                 // 1.5 MiB
    const size_t attn_bytes = (size_t)BATCH * HEADS * HDIM * HDIM * 4;  //   1 MiB
    const size_t part_bytes = (size_t)BATCH * HEADS * NSPLIT * HDIM * HDIM * 4; // 16 MiB
    const size_t wp_bytes   = (size_t)BATCH * CH * CH * 2;              //   4 MiB
    const size_t need = qk_bytes + xt_bytes + vt_bytes + wq_bytes + attn_bytes + part_bytes + wp_bytes;
    if (ws_size < need) {
        fprintf(stderr, "[kernel_launch] ws_size=%zu < need=%zu — abort\n", ws_size, need);
        fflush(stderr);
        return;
    }

    char* p = (char*)d_ws;
    bf16*  qk     = (bf16*)p;             p += qk_bytes;
    bf16*  xt     = (bf16*)p;             p += xt_bytes;
    bf16*  vt     = (bf16*)p;             p += vt_bytes;
    bf16*  wq_b   = (bf16*)p;             p += wq_bytes;
    float* attn   = (float*)p;            p += attn_bytes;
    float* part   = (float*)p;            p += part_bytes;
    bf16*  wprime = (bf16*)p;

    // 0) QKV weight convert
    convert_bf16_kernel<<<dim3((OC3 * KDEPTH + 255) / 256), 256, 0, stream>>>(
        qkv_w, wq_b, OC3 * KDEPTH);

    // 1) x -> xt (transpose + bf16)
    transpose_convert_kernel<<<dim3(NPIX / 64, KDEPTH / 64, BATCH), 256, 0, stream>>>(
        x, xt, (size_t)CH * NPIX);

    // 2) QKV GEMM: Q,K rows -> bf16 qk (c-major); V rows -> bf16 vt (transposed)
    mfma_gemm_kernel<<<dim3(NPIX / 128, OC3 / 128, BATCH), 256, 0, stream>>>(
        wq_b, xt, qkv_b, nullptr, qk, vt, QKROWS, QKROWS, 0);

    // 3) QK^T split-K + softmax
    qk_partial_kernel<<<dim3(NSPLIT, BATCH * HEADS), 256, 0, stream>>>(qk, part);
    qk_reduce_softmax_kernel<<<dim3(BATCH * HEADS), 256, 0, stream>>>(part, attn);

    // 4) attn mean over heads (output 1)
    attn_mean_kernel<<<dim3(BATCH * HDIM * HDIM / 256), 256, 0, stream>>>(attn, attn_mean);

    // 5) W' = proj_w · blockdiag(attn)
    wprime_kernel<<<dim3(CH / 64, HEADS, BATCH), 256, 0, stream>>>(proj_w, attn, wprime);

    // 6) out = W'_b · V_b + proj_b  (fp32 epilogue: qkb=nullptr, v_base huge)
    mfma_gemm_kernel<<<dim3(NPIX / 128, CH / 128, BATCH), 256, 0, stream>>>(
        wprime, vt, proj_b, out, nullptr, nullptr, 1 << 30, CH, (size_t)CH * CH);
}

// Round 9
// 180.198 us; speedup vs baseline: 6.3347x; 1.0559x over previous
//
#include <hip/hip_runtime.h>
#include <cstdio>
#include <cstdint>

// Problem constants
#define BATCH 8
#define CH    512
#define OC3   1536      // 3*CH
#define QKROWS 1024     // Q+K channel rows (bf16)
#define NPIX  4096      // 64*64
#define HEADS 8
#define HDIM  64
#define KDEPTH 512      // GEMM K
#define SCALE 0.125f    // 64^-0.5
#define NSPLIT 16       // split-K factor for QK^T (256 n per split)

typedef __bf16 bf16;
typedef __bf16 bf16x4 __attribute__((ext_vector_type(4)));
typedef __bf16 bf16x8 __attribute__((ext_vector_type(8)));
typedef float  f32x4  __attribute__((ext_vector_type(4)));

// ---------------------------------------------------------------------------
// fp32 -> bf16 flat convert (weights)
// ---------------------------------------------------------------------------
__global__ __launch_bounds__(256) void convert_bf16_kernel(
    const float* __restrict__ in, bf16* __restrict__ out, int n)
{
    const int i = blockIdx.x * 256 + threadIdx.x;
    if (i < n) out[i] = (bf16)in[i];
}

// ---------------------------------------------------------------------------
// src [b][512][4096] fp32 -> dst [b][4096][512] bf16 (transpose + convert)
// ---------------------------------------------------------------------------
__global__ __launch_bounds__(256) void transpose_convert_kernel(
    const float* __restrict__ src, bf16* __restrict__ dst, size_t src_bstride)
{
    const int b  = blockIdx.z;
    const int n0 = blockIdx.x * 64;
    const int c0 = blockIdx.y * 64;
    __shared__ float tile[64][65];
    const int t = threadIdx.x;
    const float* xp = src + (size_t)b * src_bstride;

    #pragma unroll
    for (int i = 0; i < 4; ++i) {
        const int lin = t + 256 * i;
        const int r   = lin >> 4;
        const int c4  = (lin & 15) * 4;
        const float4 v = *(const float4*)(xp + (size_t)(c0 + r) * 4096 + n0 + c4);
        tile[r][c4 + 0] = v.x; tile[r][c4 + 1] = v.y;
        tile[r][c4 + 2] = v.z; tile[r][c4 + 3] = v.w;
    }
    __syncthreads();

    bf16* op = dst + (size_t)b * 4096 * 512;
    #pragma unroll
    for (int i = 0; i < 2; ++i) {
        const int lin = t + 256 * i;
        const int n   = lin >> 3;
        const int c8  = (lin & 7) * 8;
        bf16x8 v;
        #pragma unroll
        for (int jj = 0; jj < 8; ++jj) v[jj] = (bf16)tile[c8 + jj][n];
        *(bf16x8*)(op + (size_t)(n0 + n) * 512 + c0 + c8) = v;
    }
}

// ---------------------------------------------------------------------------
// MFMA GEMM: acc[b][m][n] = sum_k A[b][m][k] * Bt[b][n][k] + bias[m]
// Epilogues:
//  - m0 >= v_base           : bf16 vt[b][n][m-v_base] via LDS transpose
//  - m0 <  v_base && qkb    : bf16 qkb[b][m][n] (Q/K rows, c-major)
//  - else                   : fp32 C[b][m][n]
// 128x128 tile, BK=32, 4 waves (2x2), global_load_lds width=16 staging.
// R9: 2-phase LDS double-buffer (stage kt+1 before computing kt) +
//     k-chunk XOR swizzle (source-preswizzled, read-swizzled; LDS dest
//     stays linear per the global_load_lds constraint) -> 2-way banks.
// ---------------------------------------------------------------------------
__global__ __launch_bounds__(256) void mfma_gemm_kernel(
    const bf16* __restrict__ A, const bf16* __restrict__ Bt,
    const float* __restrict__ bias, float* __restrict__ C,
    bf16* __restrict__ qkb, bf16* __restrict__ vt,
    int v_base, int c_rows, size_t a_bstride)
{
    const int b  = blockIdx.z;
    const int m0 = blockIdx.y * 128;
    const int n0 = blockIdx.x * 128;
    const bf16* Ap = A  + (size_t)b * a_bstride;
    const bf16* Bp = Bt + (size_t)b * NPIX * KDEPTH;

    // [2 bufs][ As 4096 | Bs 4096 ] bf16 = 32 KiB total
    __shared__ bf16 smem[16384];

    const int t    = threadIdx.x;
    const int lane = t & 63;
    const int wave = t >> 6;
    const int wr   = wave >> 1, wc = wave & 1;

    f32x4 acc[4][4];
    const f32x4 zf = {0.f, 0.f, 0.f, 0.f};
    #pragma unroll
    for (int i = 0; i < 4; ++i)
        #pragma unroll
        for (int j = 0; j < 4; ++j) acc[i][j] = zf;

    // stage K-chunk k0 into buffer p. LDS slot (row, c&3) receives global
    // k-chunk (c&3)^((row>>1)&3)  (XOR involution; read applies same XOR).
    auto STAGE = [&](int p, int k0) {
        #pragma unroll
        for (int i = 0; i < 2; ++i) {
            const int c   = t + 256 * i;    // 0..511 16B-chunks
            const int row = c >> 2;         // 0..127
            const int kb  = ((c & 3) ^ ((row >> 1) & 3)) * 8;
            __builtin_amdgcn_global_load_lds(
                (const __attribute__((address_space(1))) void*)(Ap + (size_t)(m0 + row) * KDEPTH + k0 + kb),
                (__attribute__((address_space(3))) void*)(smem + p * 8192 + c * 8), 16, 0, 0);
            __builtin_amdgcn_global_load_lds(
                (const __attribute__((address_space(1))) void*)(Bp + (size_t)(n0 + row) * KDEPTH + k0 + kb),
                (__attribute__((address_space(3))) void*)(smem + p * 8192 + 4096 + c * 8), 16, 0, 0);
        }
    };

    STAGE(0, 0);
    __syncthreads();           // compiler emits vmcnt(0) drain before barrier
    int cur = 0;

    for (int kt = 0; kt < KDEPTH / 32; ++kt) {
        if (kt < KDEPTH / 32 - 1) STAGE(cur ^ 1, (kt + 1) * 32);   // prefetch

        const bf16* AsP = smem + cur * 8192;
        const bf16* BsP = AsP + 4096;
        bf16x8 af[4], bfv[4];
        #pragma unroll
        for (int i = 0; i < 4; ++i) {
            const int ar = wr * 64 + i * 16 + (lane & 15);
            const int ja = (lane >> 4) ^ ((ar >> 1) & 3);
            af[i]  = *(const bf16x8*)(AsP + ar * 32 + ja * 8);
            const int br = wc * 64 + i * 16 + (lane & 15);
            const int jb = (lane >> 4) ^ ((br >> 1) & 3);
            bfv[i] = *(const bf16x8*)(BsP + br * 32 + jb * 8);
        }
        #pragma unroll
        for (int i = 0; i < 4; ++i)
            #pragma unroll
            for (int j = 0; j < 4; ++j)
                acc[i][j] = __builtin_amdgcn_mfma_f32_16x16x32_bf16(
                    af[i], bfv[j], acc[i][j], 0, 0, 0);

        __syncthreads();       // drains prefetch (vmcnt) + finishes reads
        cur ^= 1;
    }

    if (m0 >= v_base) {
        // fused V epilogue: bf16 + transpose -> vt[b][n][c], c = m - v_base
        const int cbase = m0 - v_base;
        bf16* vb = vt + (size_t)b * NPIX * KDEPTH;
        bf16* tb = smem;   // 64 x 132 bf16 (aliases staging bufs, dead now)
        #pragma unroll
        for (int p = 0; p < 2; ++p) {
            if (wc == p) {
                #pragma unroll
                for (int i = 0; i < 4; ++i) {
                    const int ml = wr * 64 + i * 16 + (lane >> 4) * 4;
                    #pragma unroll
                    for (int j = 0; j < 4; ++j) {
                        const int ns = j * 16 + (lane & 15);
                        bf16x4 pk;
                        #pragma unroll
                        for (int r = 0; r < 4; ++r)
                            pk[r] = (bf16)(acc[i][j][r] + bias[m0 + ml + r]);
                        *(bf16x4*)(tb + ns * 132 + ml) = pk;
                    }
                }
            }
            __syncthreads();
            #pragma unroll
            for (int ii = 0; ii < 4; ++ii) {
                const int lin = t + 256 * ii;   // 0..1023
                const int row = lin >> 4;       // n_sub 0..63
                const int seg = lin & 15;       // 8-elem segment
                const int4 v = *(const int4*)(tb + row * 132 + seg * 8);
                *(int4*)(vb + (size_t)(n0 + p * 64 + row) * KDEPTH + cbase + seg * 8) = v;
            }
            __syncthreads();
        }
    } else if (qkb) {
        // bf16 Q/K epilogue (c-major)
        bf16* Qp = qkb + (size_t)b * c_rows * NPIX;
        #pragma unroll
        for (int i = 0; i < 4; ++i) {
            const int mb = m0 + wr * 64 + i * 16 + (lane >> 4) * 4;
            #pragma unroll
            for (int r = 0; r < 4; ++r) {
                const int m  = mb + r;
                const float bv = bias[m];
                #pragma unroll
                for (int j = 0; j < 4; ++j) {
                    const int n = n0 + wc * 64 + j * 16 + (lane & 15);
                    Qp[(size_t)m * NPIX + n] = (bf16)(acc[i][j][r] + bv);
                }
            }
        }
    } else {
        // fp32 epilogue (proj GEMM -> out)
        float* Cp = C + (size_t)b * c_rows * NPIX;
        #pragma unroll
        for (int i = 0; i < 4; ++i) {
            const int mb = m0 + wr * 64 + i * 16 + (lane >> 4) * 4;
            #pragma unroll
            for (int r = 0; r < 4; ++r) {
                const int m  = mb + r;
                const float bv = bias[m];
                #pragma unroll
                for (int j = 0; j < 4; ++j) {
                    const int n = n0 + wc * 64 + j * 16 + (lane & 15);
                    Cp[(size_t)m * NPIX + n] = acc[i][j][r] + bv;
                }
            }
        }
    }
}

// ---------------------------------------------------------------------------
// QK^T split-K partial: part[bh][s][d][e] = sum_{n in split s} q[d,n]*k[e,n]
// qk: [b][1024][4096] bf16 (Q rows 0..511, K rows 512..1023). fp32 accum.
// ---------------------------------------------------------------------------
__global__ __launch_bounds__(256) void qk_partial_kernel(
    const bf16* __restrict__ qk, float* __restrict__ part)
{
    const int s  = blockIdx.x;
    const int bh = blockIdx.y;
    const int b = bh >> 3, h = bh & 7;
    const bf16* qbase = qk + ((size_t)b * QKROWS + h * HDIM) * NPIX;
    const bf16* kbase = qk + ((size_t)b * QKROWS + CH + h * HDIM) * NPIX;

    __shared__ f32x4 qs4[64 * 16];
    __shared__ f32x4 ks4[64 * 16];

    const int t  = threadIdx.x;
    const int tx = t & 15, ty = t >> 4;

    float acc[4][4] = {};

    for (int nc = 0; nc < 4; ++nc) {
        const int n0 = s * 256 + nc * 64;
        #pragma unroll
        for (int i = 0; i < 2; ++i) {
            const int lin = t + 256 * i;        // 0..511
            const int row = lin >> 3;           // 0..63
            const int s8  = lin & 7;            // 8-elem group
            const bf16x8 qv = *(const bf16x8*)(qbase + (size_t)row * NPIX + n0 + s8 * 8);
            const bf16x8 kv = *(const bf16x8*)(kbase + (size_t)row * NPIX + n0 + s8 * 8);
            f32x4 qlo = {(float)qv[0], (float)qv[1], (float)qv[2], (float)qv[3]};
            f32x4 qhi = {(float)qv[4], (float)qv[5], (float)qv[6], (float)qv[7]};
            f32x4 klo = {(float)kv[0], (float)kv[1], (float)kv[2], (float)kv[3]};
            f32x4 khi = {(float)kv[4], (float)kv[5], (float)kv[6], (float)kv[7]};
            const int m = row & 15;
            qs4[row * 16 + ((2 * s8) ^ m)]     = qlo;
            qs4[row * 16 + ((2 * s8 + 1) ^ m)] = qhi;
            ks4[row * 16 + ((2 * s8) ^ m)]     = klo;
            ks4[row * 16 + ((2 * s8 + 1) ^ m)] = khi;
        }
        __syncthreads();

        #pragma unroll
        for (int kk4 = 0; kk4 < 16; ++kk4) {
            f32x4 qf[4], kf[4];
            #pragma unroll
            for (int i = 0; i < 4; ++i)
                qf[i] = qs4[(ty + 16 * i) * 16 + (kk4 ^ ty)];
            #pragma unroll
            for (int j = 0; j < 4; ++j)
                kf[j] = ks4[(tx + 16 * j) * 16 + (kk4 ^ tx)];
            #pragma unroll
            for (int i = 0; i < 4; ++i)
                #pragma unroll
                for (int j = 0; j < 4; ++j) {
                    acc[i][j] = fmaf(qf[i][0], kf[j][0], acc[i][j]);
                    acc[i][j] = fmaf(qf[i][1], kf[j][1], acc[i][j]);
                    acc[i][j] = fmaf(qf[i][2], kf[j][2], acc[i][j]);
                    acc[i][j] = fmaf(qf[i][3], kf[j][3], acc[i][j]);
                }
        }
        __syncthreads();
    }

    float* pb = part + (((size_t)bh * NSPLIT + s) * 64) * 64;
    #pragma unroll
    for (int i = 0; i < 4; ++i)
        #pragma unroll
        for (int j = 0; j < 4; ++j)
            pb[(ty + 16 * i) * 64 + tx + 16 * j] = acc[i][j];
}

// ---------------------------------------------------------------------------
// Reduce partials + row softmax -> attn[bh][d][e] (fp32)
// ---------------------------------------------------------------------------
__global__ __launch_bounds__(256) void qk_reduce_softmax_kernel(
    const float* __restrict__ part, float* __restrict__ attn)
{
    const int bh = blockIdx.x;
    const int t  = threadIdx.x;
    const int r  = t >> 2;
    const int e0 = (t & 3) * 16;

    float v[16];
    #pragma unroll
    for (int i = 0; i < 16; ++i) v[i] = 0.f;

    const float* pb = part + ((size_t)bh * NSPLIT * 64) * 64 + r * 64 + e0;
    for (int s = 0; s < NSPLIT; ++s) {
        const float* ps = pb + (size_t)s * 4096;
        #pragma unroll
        for (int c4 = 0; c4 < 4; ++c4) {
            const float4 p = *(const float4*)(ps + c4 * 4);
            v[c4 * 4 + 0] += p.x; v[c4 * 4 + 1] += p.y;
            v[c4 * 4 + 2] += p.z; v[c4 * 4 + 3] += p.w;
        }
    }

    float m = -1e30f;
    #pragma unroll
    for (int i = 0; i < 16; ++i) m = fmaxf(m, v[i]);
    m = fmaxf(m, __shfl_xor(m, 1));
    m = fmaxf(m, __shfl_xor(m, 2));

    float sum = 0.f;
    #pragma unroll
    for (int i = 0; i < 16; ++i) {
        v[i] = __expf((v[i] - m) * SCALE);
        sum += v[i];
    }
    sum += __shfl_xor(sum, 1);
    sum += __shfl_xor(sum, 2);
    const float inv = 1.f / sum;

    float* arow = attn + ((size_t)bh * 64 + r) * 64 + e0;
    #pragma unroll
    for (int c4 = 0; c4 < 4; ++c4) {
        float4 o;
        o.x = v[c4 * 4 + 0] * inv; o.y = v[c4 * 4 + 1] * inv;
        o.z = v[c4 * 4 + 2] * inv; o.w = v[c4 * 4 + 3] * inv;
        *(float4*)(arow + c4 * 4) = o;
    }
}

// ---------------------------------------------------------------------------
// attn_mean[b][d][e] = mean_h attn[b][h][d][e]
// ---------------------------------------------------------------------------
__global__ __launch_bounds__(256) void attn_mean_kernel(
    const float* __restrict__ attn, float* __restrict__ om)
{
    const int idx = blockIdx.x * 256 + threadIdx.x;
    const int b = idx >> 12, de = idx & 4095;
    float s = 0.f;
    #pragma unroll
    for (int h = 0; h < 8; ++h)
        s += attn[(((size_t)b * 8 + h) << 12) + de];
    om[idx] = s * 0.125f;
}

// ---------------------------------------------------------------------------
// W'[b][o][h*64+e] = sum_d proj_w[o][h*64+d] * attn[b,h,d,e]   (fp32 -> bf16)
// ---------------------------------------------------------------------------
__global__ __launch_bounds__(256) void wprime_kernel(
    const float* __restrict__ proj_w, const float* __restrict__ attn,
    bf16* __restrict__ wp)
{
    const int o0 = blockIdx.x * 64;
    const int h  = blockIdx.y;
    const int b  = blockIdx.z;

    __shared__ float ws[64][65];   // proj_w[o_local][d]
    __shared__ float as_[64][65];  // attn[d][e]

    const int t = threadIdx.x;
    #pragma unroll
    for (int i = 0; i < 4; ++i) {
        const int lin = t + 256 * i;      // 0..1023
        const int r   = lin >> 4;         // 0..63
        const int c4  = (lin & 15) * 4;
        const float4 wv = *(const float4*)(proj_w + (size_t)(o0 + r) * CH + h * HDIM + c4);
        ws[r][c4 + 0] = wv.x; ws[r][c4 + 1] = wv.y;
        ws[r][c4 + 2] = wv.z; ws[r][c4 + 3] = wv.w;
        const float4 av = *(const float4*)(attn + (((size_t)(b * 8 + h) * 64) + r) * 64 + c4);
        as_[r][c4 + 0] = av.x; as_[r][c4 + 1] = av.y;
        as_[r][c4 + 2] = av.z; as_[r][c4 + 3] = av.w;
    }
    __syncthreads();

    const int tx = t & 15, ty = t >> 4;
    const int to = ty * 4, te = tx * 4;
    float acc[4][4] = {};
    for (int d = 0; d < 64; ++d) {
        float a[4], bb[4];
        #pragma unroll
        for (int i = 0; i < 4; ++i) a[i]  = ws[to + i][d];
        #pragma unroll
        for (int j = 0; j < 4; ++j) bb[j] = as_[d][te + j];
        #pragma unroll
        for (int i = 0; i < 4; ++i)
            #pragma unroll
            for (int j = 0; j < 4; ++j)
                acc[i][j] = fmaf(a[i], bb[j], acc[i][j]);
    }

    bf16* wb = wp + (size_t)b * CH * CH;
    #pragma unroll
    for (int i = 0; i < 4; ++i)
        #pragma unroll
        for (int j = 0; j < 4; ++j)
            wb[(size_t)(o0 + to + i) * CH + h * HDIM + te + j] = (bf16)acc[i][j];
}

// ---------------------------------------------------------------------------
extern "C" void kernel_launch(void* const* d_in, const int* in_sizes, int n_in,
                              void* d_out, int out_size, void* d_ws, size_t ws_size,
                              hipStream_t stream)
{
    (void)in_sizes; (void)n_in; (void)out_size;
    const float* x      = (const float*)d_in[0];
    const float* qkv_w  = (const float*)d_in[1];
    const float* qkv_b  = (const float*)d_in[2];
    const float* proj_w = (const float*)d_in[3];
    const float* proj_b = (const float*)d_in[4];

    float* out       = (float*)d_out;
    float* attn_mean = out + (size_t)BATCH * CH * NPIX;

    const size_t qk_bytes   = (size_t)BATCH * QKROWS * NPIX * 2;        //  64 MiB (bf16)
    const size_t xt_bytes   = (size_t)BATCH * NPIX * KDEPTH * 2;        //  32 MiB
    const size_t vt_bytes   = (size_t)BATCH * NPIX * KDEPTH * 2;        //  32 MiB
    const size_t wq_bytes   = (size_t)OC3 * KDEPTH * 2;                 // 1.5 MiB
    const size_t attn_bytes = (size_t)BATCH * HEADS * HDIM * HDIM * 4;  //   1 MiB
    const size_t part_bytes = (size_t)BATCH * HEADS * NSPLIT * HDIM * HDIM * 4; // 16 MiB
    const size_t wp_bytes   = (size_t)BATCH * CH * CH * 2;              //   4 MiB
    const size_t need = qk_bytes + xt_bytes + vt_bytes + wq_bytes + attn_bytes + part_bytes + wp_bytes;
    if (ws_size < need) {
        fprintf(stderr, "[kernel_launch] ws_size=%zu < need=%zu — abort\n", ws_size, need);
        fflush(stderr);
        return;
    }

    char* p = (char*)d_ws;
    bf16*  qk     = (bf16*)p;             p += qk_bytes;
    bf16*  xt     = (bf16*)p;             p += xt_bytes;
    bf16*  vt     = (bf16*)p;             p += vt_bytes;
    bf16*  wq_b   = (bf16*)p;             p += wq_bytes;
    float* attn   = (float*)p;            p += attn_bytes;
    float* part   = (float*)p;            p += part_bytes;
    bf16*  wprime = (bf16*)p;

    // 0) QKV weight convert
    convert_bf16_kernel<<<dim3((OC3 * KDEPTH + 255) / 256), 256, 0, stream>>>(
        qkv_w, wq_b, OC3 * KDEPTH);

    // 1) x -> xt (transpose + bf16)
    transpose_convert_kernel<<<dim3(NPIX / 64, KDEPTH / 64, BATCH), 256, 0, stream>>>(
        x, xt, (size_t)CH * NPIX);

    // 2) QKV GEMM: Q,K rows -> bf16 qk (c-major); V rows -> bf16 vt (transposed)
    mfma_gemm_kernel<<<dim3(NPIX / 128, OC3 / 128, BATCH), 256, 0, stream>>>(
        wq_b, xt, qkv_b, nullptr, qk, vt, QKROWS, QKROWS, 0);

    // 3) QK^T split-K + softmax
    qk_partial_kernel<<<dim3(NSPLIT, BATCH * HEADS), 256, 0, stream>>>(qk, part);
    qk_reduce_softmax_kernel<<<dim3(BATCH * HEADS), 256, 0, stream>>>(part, attn);

    // 4) attn mean over heads (output 1)
    attn_mean_kernel<<<dim3(BATCH * HDIM * HDIM / 256), 256, 0, stream>>>(attn, attn_mean);

    // 5) W' = proj_w · blockdiag(attn)
    wprime_kernel<<<dim3(CH / 64, HEADS, BATCH), 256, 0, stream>>>(proj_w, attn, wprime);

    // 6) out = W'_b · V_b + proj_b  (fp32 epilogue: qkb=nullptr, v_base huge)
    mfma_gemm_kernel<<<dim3(NPIX / 128, CH / 128, BATCH), 256, 0, stream>>>(
        wprime, vt, proj_b, out, nullptr, nullptr, 1 << 30, CH, (size_t)CH * CH);
}

// Round 10
// 161.473 us; speedup vs baseline: 7.0693x; 1.1160x over previous
//
#include <hip/hip_runtime.h>
#include <cstdio>
#include <cstdint>

// Problem constants
#define BATCH 8
#define CH    512
#define OC3   1536      // 3*CH
#define QKROWS 1024     // Q+K channel rows (bf16)
#define NPIX  4096      // 64*64
#define HEADS 8
#define HDIM  64
#define KDEPTH 512      // GEMM K
#define SCALE 0.125f    // 64^-0.5
#define NSPLIT 16       // split-K factor for QK^T (256 n per split)

typedef __bf16 bf16;
typedef __bf16 bf16x4 __attribute__((ext_vector_type(4)));
typedef __bf16 bf16x8 __attribute__((ext_vector_type(8)));
typedef float  f32x4  __attribute__((ext_vector_type(4)));

// ---------------------------------------------------------------------------
// fp32 -> bf16 flat convert (weights)
// ---------------------------------------------------------------------------
__global__ __launch_bounds__(256) void convert_bf16_kernel(
    const float* __restrict__ in, bf16* __restrict__ out, int n)
{
    const int i = blockIdx.x * 256 + threadIdx.x;
    if (i < n) out[i] = (bf16)in[i];
}

// ---------------------------------------------------------------------------
// src [b][512][4096] fp32 -> dst [b][4096][512] bf16 (transpose + convert)
// ---------------------------------------------------------------------------
__global__ __launch_bounds__(256) void transpose_convert_kernel(
    const float* __restrict__ src, bf16* __restrict__ dst, size_t src_bstride)
{
    const int b  = blockIdx.z;
    const int n0 = blockIdx.x * 64;
    const int c0 = blockIdx.y * 64;
    __shared__ float tile[64][65];
    const int t = threadIdx.x;
    const float* xp = src + (size_t)b * src_bstride;

    #pragma unroll
    for (int i = 0; i < 4; ++i) {
        const int lin = t + 256 * i;
        const int r   = lin >> 4;
        const int c4  = (lin & 15) * 4;
        const float4 v = *(const float4*)(xp + (size_t)(c0 + r) * 4096 + n0 + c4);
        tile[r][c4 + 0] = v.x; tile[r][c4 + 1] = v.y;
        tile[r][c4 + 2] = v.z; tile[r][c4 + 3] = v.w;
    }
    __syncthreads();

    bf16* op = dst + (size_t)b * 4096 * 512;
    #pragma unroll
    for (int i = 0; i < 2; ++i) {
        const int lin = t + 256 * i;
        const int n   = lin >> 3;
        const int c8  = (lin & 7) * 8;
        bf16x8 v;
        #pragma unroll
        for (int jj = 0; jj < 8; ++jj) v[jj] = (bf16)tile[c8 + jj][n];
        *(bf16x8*)(op + (size_t)(n0 + n) * 512 + c0 + c8) = v;
    }
}

// ---------------------------------------------------------------------------
// MFMA GEMM: acc[b][m][n] = sum_k A[b][m][k] * Bt[b][n][k] + bias[m]
// Epilogues:
//  - m0 >= v_base           : bf16 vt[b][n][m-v_base] via LDS transpose
//  - m0 <  v_base && qkb    : bf16 qkb[b][m][n] (Q/K rows, c-major)
//  - else                   : fp32 C[b][m][n]
// 128x128 tile, BK=32, 4 waves (2x2), global_load_lds width=16 staging,
// 2-phase LDS double-buffer + both-sides k-chunk XOR swizzle.
// ---------------------------------------------------------------------------
__global__ __launch_bounds__(256) void mfma_gemm_kernel(
    const bf16* __restrict__ A, const bf16* __restrict__ Bt,
    const float* __restrict__ bias, float* __restrict__ C,
    bf16* __restrict__ qkb, bf16* __restrict__ vt,
    int v_base, int c_rows, size_t a_bstride)
{
    const int b  = blockIdx.z;
    const int m0 = blockIdx.y * 128;
    const int n0 = blockIdx.x * 128;
    const bf16* Ap = A  + (size_t)b * a_bstride;
    const bf16* Bp = Bt + (size_t)b * NPIX * KDEPTH;

    // [2 bufs][ As 4096 | Bs 4096 ] bf16 = 32 KiB total
    __shared__ bf16 smem[16384];

    const int t    = threadIdx.x;
    const int lane = t & 63;
    const int wave = t >> 6;
    const int wr   = wave >> 1, wc = wave & 1;

    f32x4 acc[4][4];
    const f32x4 zf = {0.f, 0.f, 0.f, 0.f};
    #pragma unroll
    for (int i = 0; i < 4; ++i)
        #pragma unroll
        for (int j = 0; j < 4; ++j) acc[i][j] = zf;

    auto STAGE = [&](int p, int k0) {
        #pragma unroll
        for (int i = 0; i < 2; ++i) {
            const int c   = t + 256 * i;    // 0..511 16B-chunks
            const int row = c >> 2;         // 0..127
            const int kb  = ((c & 3) ^ ((row >> 1) & 3)) * 8;
            __builtin_amdgcn_global_load_lds(
                (const __attribute__((address_space(1))) void*)(Ap + (size_t)(m0 + row) * KDEPTH + k0 + kb),
                (__attribute__((address_space(3))) void*)(smem + p * 8192 + c * 8), 16, 0, 0);
            __builtin_amdgcn_global_load_lds(
                (const __attribute__((address_space(1))) void*)(Bp + (size_t)(n0 + row) * KDEPTH + k0 + kb),
                (__attribute__((address_space(3))) void*)(smem + p * 8192 + 4096 + c * 8), 16, 0, 0);
        }
    };

    STAGE(0, 0);
    __syncthreads();
    int cur = 0;

    for (int kt = 0; kt < KDEPTH / 32; ++kt) {
        if (kt < KDEPTH / 32 - 1) STAGE(cur ^ 1, (kt + 1) * 32);   // prefetch

        const bf16* AsP = smem + cur * 8192;
        const bf16* BsP = AsP + 4096;
        bf16x8 af[4], bfv[4];
        #pragma unroll
        for (int i = 0; i < 4; ++i) {
            const int ar = wr * 64 + i * 16 + (lane & 15);
            const int ja = (lane >> 4) ^ ((ar >> 1) & 3);
            af[i]  = *(const bf16x8*)(AsP + ar * 32 + ja * 8);
            const int br = wc * 64 + i * 16 + (lane & 15);
            const int jb = (lane >> 4) ^ ((br >> 1) & 3);
            bfv[i] = *(const bf16x8*)(BsP + br * 32 + jb * 8);
        }
        #pragma unroll
        for (int i = 0; i < 4; ++i)
            #pragma unroll
            for (int j = 0; j < 4; ++j)
                acc[i][j] = __builtin_amdgcn_mfma_f32_16x16x32_bf16(
                    af[i], bfv[j], acc[i][j], 0, 0, 0);

        __syncthreads();
        cur ^= 1;
    }

    if (m0 >= v_base) {
        // fused V epilogue: bf16 + transpose -> vt[b][n][c], c = m - v_base
        const int cbase = m0 - v_base;
        bf16* vb = vt + (size_t)b * NPIX * KDEPTH;
        bf16* tb = smem;   // 64 x 132 bf16 (aliases staging bufs, dead now)
        #pragma unroll
        for (int p = 0; p < 2; ++p) {
            if (wc == p) {
                #pragma unroll
                for (int i = 0; i < 4; ++i) {
                    const int ml = wr * 64 + i * 16 + (lane >> 4) * 4;
                    #pragma unroll
                    for (int j = 0; j < 4; ++j) {
                        const int ns = j * 16 + (lane & 15);
                        bf16x4 pk;
                        #pragma unroll
                        for (int r = 0; r < 4; ++r)
                            pk[r] = (bf16)(acc[i][j][r] + bias[m0 + ml + r]);
                        *(bf16x4*)(tb + ns * 132 + ml) = pk;
                    }
                }
            }
            __syncthreads();
            #pragma unroll
            for (int ii = 0; ii < 4; ++ii) {
                const int lin = t + 256 * ii;   // 0..1023
                const int row = lin >> 4;       // n_sub 0..63
                const int seg = lin & 15;       // 8-elem segment
                const int4 v = *(const int4*)(tb + row * 132 + seg * 8);
                *(int4*)(vb + (size_t)(n0 + p * 64 + row) * KDEPTH + cbase + seg * 8) = v;
            }
            __syncthreads();
        }
    } else if (qkb) {
        // bf16 Q/K epilogue (c-major)
        bf16* Qp = qkb + (size_t)b * c_rows * NPIX;
        #pragma unroll
        for (int i = 0; i < 4; ++i) {
            const int mb = m0 + wr * 64 + i * 16 + (lane >> 4) * 4;
            #pragma unroll
            for (int r = 0; r < 4; ++r) {
                const int m  = mb + r;
                const float bv = bias[m];
                #pragma unroll
                for (int j = 0; j < 4; ++j) {
                    const int n = n0 + wc * 64 + j * 16 + (lane & 15);
                    Qp[(size_t)m * NPIX + n] = (bf16)(acc[i][j][r] + bv);
                }
            }
        }
    } else {
        // fp32 epilogue (proj GEMM -> out)
        float* Cp = C + (size_t)b * c_rows * NPIX;
        #pragma unroll
        for (int i = 0; i < 4; ++i) {
            const int mb = m0 + wr * 64 + i * 16 + (lane >> 4) * 4;
            #pragma unroll
            for (int r = 0; r < 4; ++r) {
                const int m  = mb + r;
                const float bv = bias[m];
                #pragma unroll
                for (int j = 0; j < 4; ++j) {
                    const int n = n0 + wc * 64 + j * 16 + (lane & 15);
                    Cp[(size_t)m * NPIX + n] = acc[i][j][r] + bv;
                }
            }
        }
    }
}

// ---------------------------------------------------------------------------
// QK^T split-K partial (MFMA): part[bh][s][d][e] = sum_{n in split} q[d,n]k[e,n]
// qk: [b][1024][4096] bf16. Block (s,bh): 64x64 output over 256 n.
// 4 waves: wave w computes d rows 16w..16w+15, all 64 e.
// LDS: [2 bufs][Qs 64x64 | Ks 64x64] bf16, chunk XOR swizzle j^(row&7),
// staged via global_load_lds (linear dest, pre-swizzled source).
// ---------------------------------------------------------------------------
__global__ __launch_bounds__(256) void qk_partial_kernel(
    const bf16* __restrict__ qk, float* __restrict__ part)
{
    const int s  = blockIdx.x;
    const int bh = blockIdx.y;
    const int b = bh >> 3, h = bh & 7;
    const bf16* qbase = qk + ((size_t)b * QKROWS + h * HDIM) * NPIX;
    const bf16* kbase = qk + ((size_t)b * QKROWS + CH + h * HDIM) * NPIX;

    __shared__ bf16 smem[16384];   // 32 KiB: 2 x (Qs 4096 | Ks 4096)

    const int t    = threadIdx.x;
    const int lane = t & 63;
    const int wave = t >> 6;

    f32x4 acc[4];
    const f32x4 zf = {0.f, 0.f, 0.f, 0.f};
    #pragma unroll
    for (int j = 0; j < 4; ++j) acc[j] = zf;

    auto STAGE = [&](int p, int n0) {
        #pragma unroll
        for (int i = 0; i < 2; ++i) {
            const int c   = t + 256 * i;    // 0..511 16B-chunks
            const int row = c >> 3;         // 0..63
            const int nb  = ((c & 7) ^ (row & 7)) * 8;   // pre-swizzled source
            __builtin_amdgcn_global_load_lds(
                (const __attribute__((address_space(1))) void*)(qbase + (size_t)row * NPIX + n0 + nb),
                (__attribute__((address_space(3))) void*)(smem + p * 8192 + c * 8), 16, 0, 0);
            __builtin_amdgcn_global_load_lds(
                (const __attribute__((address_space(1))) void*)(kbase + (size_t)row * NPIX + n0 + nb),
                (__attribute__((address_space(3))) void*)(smem + p * 8192 + 4096 + c * 8), 16, 0, 0);
        }
    };

    STAGE(0, s * 256);
    __syncthreads();
    int cur = 0;

    for (int nc = 0; nc < 4; ++nc) {
        if (nc < 3) STAGE(cur ^ 1, s * 256 + (nc + 1) * 64);   // prefetch

        const bf16* Qs = smem + cur * 8192;
        const bf16* Ks = Qs + 4096;
        #pragma unroll
        for (int ks = 0; ks < 2; ++ks) {
            const int dr = wave * 16 + (lane & 15);
            const int ja = (ks * 4 + (lane >> 4)) ^ (dr & 7);
            const bf16x8 af = *(const bf16x8*)(Qs + dr * 64 + ja * 8);
            #pragma unroll
            for (int j = 0; j < 4; ++j) {
                const int er = j * 16 + (lane & 15);
                const int jb = (ks * 4 + (lane >> 4)) ^ (er & 7);
                const bf16x8 bf_ = *(const bf16x8*)(Ks + er * 64 + jb * 8);
                acc[j] = __builtin_amdgcn_mfma_f32_16x16x32_bf16(af, bf_, acc[j], 0, 0, 0);
            }
        }
        __syncthreads();
        cur ^= 1;
    }

    // D layout: col e = lane&15 (within 16-tile j), row d = (lane>>4)*4 + r
    float* pb = part + (((size_t)bh * NSPLIT + s) * 64) * 64;
    #pragma unroll
    for (int j = 0; j < 4; ++j)
        #pragma unroll
        for (int r = 0; r < 4; ++r)
            pb[(size_t)(wave * 16 + (lane >> 4) * 4 + r) * 64 + j * 16 + (lane & 15)] = acc[j][r];
}

// ---------------------------------------------------------------------------
// Reduce partials + row softmax -> attn[bh][d][e] (fp32)
// ---------------------------------------------------------------------------
__global__ __launch_bounds__(256) void qk_reduce_softmax_kernel(
    const float* __restrict__ part, float* __restrict__ attn)
{
    const int bh = blockIdx.x;
    const int t  = threadIdx.x;
    const int r  = t >> 2;
    const int e0 = (t & 3) * 16;

    float v[16];
    #pragma unroll
    for (int i = 0; i < 16; ++i) v[i] = 0.f;

    const float* pb = part + ((size_t)bh * NSPLIT * 64) * 64 + r * 64 + e0;
    for (int s = 0; s < NSPLIT; ++s) {
        const float* ps = pb + (size_t)s * 4096;
        #pragma unroll
        for (int c4 = 0; c4 < 4; ++c4) {
            const float4 p = *(const float4*)(ps + c4 * 4);
            v[c4 * 4 + 0] += p.x; v[c4 * 4 + 1] += p.y;
            v[c4 * 4 + 2] += p.z; v[c4 * 4 + 3] += p.w;
        }
    }

    float m = -1e30f;
    #pragma unroll
    for (int i = 0; i < 16; ++i) m = fmaxf(m, v[i]);
    m = fmaxf(m, __shfl_xor(m, 1));
    m = fmaxf(m, __shfl_xor(m, 2));

    float sum = 0.f;
    #pragma unroll
    for (int i = 0; i < 16; ++i) {
        v[i] = __expf((v[i] - m) * SCALE);
        sum += v[i];
    }
    sum += __shfl_xor(sum, 1);
    sum += __shfl_xor(sum, 2);
    const float inv = 1.f / sum;

    float* arow = attn + ((size_t)bh * 64 + r) * 64 + e0;
    #pragma unroll
    for (int c4 = 0; c4 < 4; ++c4) {
        float4 o;
        o.x = v[c4 * 4 + 0] * inv; o.y = v[c4 * 4 + 1] * inv;
        o.z = v[c4 * 4 + 2] * inv; o.w = v[c4 * 4 + 3] * inv;
        *(float4*)(arow + c4 * 4) = o;
    }
}

// ---------------------------------------------------------------------------
// attn_mean[b][d][e] = mean_h attn[b][h][d][e]
// ---------------------------------------------------------------------------
__global__ __launch_bounds__(256) void attn_mean_kernel(
    const float* __restrict__ attn, float* __restrict__ om)
{
    const int idx = blockIdx.x * 256 + threadIdx.x;
    const int b = idx >> 12, de = idx & 4095;
    float s = 0.f;
    #pragma unroll
    for (int h = 0; h < 8; ++h)
        s += attn[(((size_t)b * 8 + h) << 12) + de];
    om[idx] = s * 0.125f;
}

// ---------------------------------------------------------------------------
// W'[b][o][h*64+e] = sum_d proj_w[o][h*64+d] * attn[b,h,d,e]   (fp32 -> bf16)
// ---------------------------------------------------------------------------
__global__ __launch_bounds__(256) void wprime_kernel(
    const float* __restrict__ proj_w, const float* __restrict__ attn,
    bf16* __restrict__ wp)
{
    const int o0 = blockIdx.x * 64;
    const int h  = blockIdx.y;
    const int b  = blockIdx.z;

    __shared__ float ws[64][65];   // proj_w[o_local][d]
    __shared__ float as_[64][65];  // attn[d][e]

    const int t = threadIdx.x;
    #pragma unroll
    for (int i = 0; i < 4; ++i) {
        const int lin = t + 256 * i;      // 0..1023
        const int r   = lin >> 4;         // 0..63
        const int c4  = (lin & 15) * 4;
        const float4 wv = *(const float4*)(proj_w + (size_t)(o0 + r) * CH + h * HDIM + c4);
        ws[r][c4 + 0] = wv.x; ws[r][c4 + 1] = wv.y;
        ws[r][c4 + 2] = wv.z; ws[r][c4 + 3] = wv.w;
        const float4 av = *(const float4*)(attn + (((size_t)(b * 8 + h) * 64) + r) * 64 + c4);
        as_[r][c4 + 0] = av.x; as_[r][c4 + 1] = av.y;
        as_[r][c4 + 2] = av.z; as_[r][c4 + 3] = av.w;
    }
    __syncthreads();

    const int tx = t & 15, ty = t >> 4;
    const int to = ty * 4, te = tx * 4;
    float acc[4][4] = {};
    for (int d = 0; d < 64; ++d) {
        float a[4], bb[4];
        #pragma unroll
        for (int i = 0; i < 4; ++i) a[i]  = ws[to + i][d];
        #pragma unroll
        for (int j = 0; j < 4; ++j) bb[j] = as_[d][te + j];
        #pragma unroll
        for (int i = 0; i < 4; ++i)
            #pragma unroll
            for (int j = 0; j < 4; ++j)
                acc[i][j] = fmaf(a[i], bb[j], acc[i][j]);
    }

    bf16* wb = wp + (size_t)b * CH * CH;
    #pragma unroll
    for (int i = 0; i < 4; ++i)
        #pragma unroll
        for (int j = 0; j < 4; ++j)
            wb[(size_t)(o0 + to + i) * CH + h * HDIM + te + j] = (bf16)acc[i][j];
}

// ---------------------------------------------------------------------------
extern "C" void kernel_launch(void* const* d_in, const int* in_sizes, int n_in,
                              void* d_out, int out_size, void* d_ws, size_t ws_size,
                              hipStream_t stream)
{
    (void)in_sizes; (void)n_in; (void)out_size;
    const float* x      = (const float*)d_in[0];
    const float* qkv_w  = (const float*)d_in[1];
    const float* qkv_b  = (const float*)d_in[2];
    const float* proj_w = (const float*)d_in[3];
    const float* proj_b = (const float*)d_in[4];

    float* out       = (float*)d_out;
    float* attn_mean = out + (size_t)BATCH * CH * NPIX;

    const size_t qk_bytes   = (size_t)BATCH * QKROWS * NPIX * 2;        //  64 MiB (bf16)
    const size_t xt_bytes   = (size_t)BATCH * NPIX * KDEPTH * 2;        //  32 MiB
    const size_t vt_bytes   = (size_t)BATCH * NPIX * KDEPTH * 2;        //  32 MiB
    const size_t wq_bytes   = (size_t)OC3 * KDEPTH * 2;                 // 1.5 MiB
    const size_t attn_bytes = (size_t)BATCH * HEADS * HDIM * HDIM * 4;  //   1 MiB
    const size_t part_bytes = (size_t)BATCH * HEADS * NSPLIT * HDIM * HDIM * 4; // 16 MiB
    const size_t wp_bytes   = (size_t)BATCH * CH * CH * 2;              //   4 MiB
    const size_t need = qk_bytes + xt_bytes + vt_bytes + wq_bytes + attn_bytes + part_bytes + wp_bytes;
    if (ws_size < need) {
        fprintf(stderr, "[kernel_launch] ws_size=%zu < need=%zu — abort\n", ws_size, need);
        fflush(stderr);
        return;
    }

    char* p = (char*)d_ws;
    bf16*  qk     = (bf16*)p;             p += qk_bytes;
    bf16*  xt     = (bf16*)p;             p += xt_bytes;
    bf16*  vt     = (bf16*)p;             p += vt_bytes;
    bf16*  wq_b   = (bf16*)p;             p += wq_bytes;
    float* attn   = (float*)p;            p += attn_bytes;
    float* part   = (float*)p;            p += part_bytes;
    bf16*  wprime = (bf16*)p;

    // 0) QKV weight convert
    convert_bf16_kernel<<<dim3((OC3 * KDEPTH + 255) / 256), 256, 0, stream>>>(
        qkv_w, wq_b, OC3 * KDEPTH);

    // 1) x -> xt (transpose + bf16)
    transpose_convert_kernel<<<dim3(NPIX / 64, KDEPTH / 64, BATCH), 256, 0, stream>>>(
        x, xt, (size_t)CH * NPIX);

    // 2) QKV GEMM: Q,K rows -> bf16 qk (c-major); V rows -> bf16 vt (transposed)
    mfma_gemm_kernel<<<dim3(NPIX / 128, OC3 / 128, BATCH), 256, 0, stream>>>(
        wq_b, xt, qkv_b, nullptr, qk, vt, QKROWS, QKROWS, 0);

    // 3) QK^T split-K (MFMA) + softmax
    qk_partial_kernel<<<dim3(NSPLIT, BATCH * HEADS), 256, 0, stream>>>(qk, part);
    qk_reduce_softmax_kernel<<<dim3(BATCH * HEADS), 256, 0, stream>>>(part, attn);

    // 4) attn mean over heads (output 1)
    attn_mean_kernel<<<dim3(BATCH * HDIM * HDIM / 256), 256, 0, stream>>>(attn, attn_mean);

    // 5) W' = proj_w · blockdiag(attn)
    wprime_kernel<<<dim3(CH / 64, HEADS, BATCH), 256, 0, stream>>>(proj_w, attn, wprime);

    // 6) out = W'_b · V_b + proj_b  (fp32 epilogue: qkb=nullptr, v_base huge)
    mfma_gemm_kernel<<<dim3(NPIX / 128, CH / 128, BATCH), 256, 0, stream>>>(
        wprime, vt, proj_b, out, nullptr, nullptr, 1 << 30, CH, (size_t)CH * CH);
}